// Round 6
// baseline (225.130 us; speedup 1.0000x reference)
//
#include <hip/hip_runtime.h>
#include <math.h>

#define B_ 4
#define C_ 512
#define L_ 2048
#define H_ 8
#define D_ 64
// 0.125 * log2(e): folded into Q so softmax uses exp2 (raw v_exp_f32)
#define QSCALE 0.18033688011112042f
#define DEFER_THR 12.0f

typedef __bf16 bf16x8 __attribute__((ext_vector_type(8)));
typedef float f32x4 __attribute__((ext_vector_type(4)));

__device__ __forceinline__ unsigned cvt_pk(float lo, float hi) {
    unsigned r;
    asm("v_cvt_pk_bf16_f32 %0, %1, %2" : "=v"(r) : "v"(lo), "v"(hi));
    return r;
}
__device__ __forceinline__ unsigned short f2bf_hw(float a) {
    unsigned r;
    asm("v_cvt_pk_bf16_f32 %0, %1, %1" : "=v"(r) : "v"(a));
    return (unsigned short)r;
}
__device__ __forceinline__ bf16x8 frag_ld(const unsigned short* p) {
    uint4 v = *reinterpret_cast<const uint4*>(p);
    return __builtin_bit_cast(bf16x8, v);
}
__device__ __forceinline__ float fmax3(float a, float b, float c) {
    return fmaxf(fmaxf(a, b), c);   // clang fuses to v_max3_f32
}
// async global->LDS, 16B per lane; LDS dest = wave-uniform base + lane*16
__device__ __forceinline__ void glds16(const void* g, void* l) {
    __builtin_amdgcn_global_load_lds(
        (const __attribute__((address_space(1))) void*)g,
        (__attribute__((address_space(3))) void*)l, 16, 0, 0);
}

// =====================================================================
// prep: z<4  -> transpose x (B,C,L) f32 -> xt (B,L,C) bf16 (64x64 tiles)
//       z>=4 -> convert weight matrix (z-4) f32 -> bf16
// =====================================================================
__global__ __launch_bounds__(256) void prep(
    const float* __restrict__ x,
    const float* __restrict__ w0, const float* __restrict__ w1,
    const float* __restrict__ w2, const float* __restrict__ w3,
    unsigned short* __restrict__ xt,
    unsigned short* __restrict__ o0, unsigned short* __restrict__ o1,
    unsigned short* __restrict__ o2, unsigned short* __restrict__ o3)
{
    __shared__ float T[64][68];
    const int t = threadIdx.x;

    if (blockIdx.z < B_) {
        const int b  = blockIdx.z;
        const int l0 = blockIdx.x * 64;
        const int c0 = blockIdx.y * 64;
        const float* xb = x + (size_t)b * C_ * L_;
        unsigned short* xtb = xt + (size_t)b * L_ * C_;

        #pragma unroll
        for (int p = 0; p < 4; ++p) {
            const int ci = 16 * p + (t >> 4);
            const int l4 = (t & 15) * 4;
            *reinterpret_cast<float4*>(&T[ci][l4]) =
                *reinterpret_cast<const float4*>(xb + (size_t)(c0 + ci) * L_ + l0 + l4);
        }
        __syncthreads();

        const int lo = t >> 2;
        const int cb = (t & 3) * 16;
        unsigned w[8];
        #pragma unroll
        for (int k = 0; k < 8; ++k)
            w[k] = cvt_pk(T[cb + 2 * k][lo], T[cb + 2 * k + 1][lo]);
        unsigned short* dst = xtb + (size_t)(l0 + lo) * C_ + c0 + cb;
        *reinterpret_cast<uint4*>(dst)     = make_uint4(w[0], w[1], w[2], w[3]);
        *reinterpret_cast<uint4*>(dst + 8) = make_uint4(w[4], w[5], w[6], w[7]);
    } else {
        const int m = blockIdx.z - B_;
        const float* src; unsigned short* dst;
        if      (m == 0) { src = w0; dst = o0; }
        else if (m == 1) { src = w1; dst = o1; }
        else if (m == 2) { src = w2; dst = o2; }
        else             { src = w3; dst = o3; }
        const int flat = blockIdx.x + 32 * blockIdx.y;   // 0..255
        const size_t idx = ((size_t)flat * 256 + t) * 4;
        const float4 v = *reinterpret_cast<const float4*>(src + idx);
        *reinterpret_cast<uint2*>(dst + idx) =
            make_uint2(cvt_pk(v.x, v.y), cvt_pk(v.z, v.w));
    }
}

// =====================================================================
// qkv_gemm: fused Q/K/V projections, 2-phase glds double-buffer.
// mode 0: qb[l][c] = (xt Wq^T + bq) * QSCALE           (unswizzled)
// mode 1: kb[l][c] =  xt Wk^T + bk   (stored with n ^= (m&7)<<3 swizzle)
// mode 2: vb[c][l] =  Wv xt^T + bv   (stored with n ^= (m&7)<<3 swizzle)
// Tile 128x128, BK=32, 4 waves (2x2). grid (4,16,12) = 768 blocks.
// =====================================================================
__global__ __launch_bounds__(256) void qkv_gemm(
    const unsigned short* __restrict__ xt,
    const unsigned short* __restrict__ wq, const unsigned short* __restrict__ wk,
    const unsigned short* __restrict__ wv,
    const float* __restrict__ bq, const float* __restrict__ bk,
    const float* __restrict__ bv,
    unsigned short* __restrict__ qb, unsigned short* __restrict__ kb,
    unsigned short* __restrict__ vb)
{
    __shared__ unsigned short As[2][128][32];
    __shared__ unsigned short Bs[2][128][32];

    const int mode = blockIdx.z >> 2;
    const int b    = blockIdx.z & 3;
    const size_t LC = (size_t)L_ * C_;

    const unsigned short *A, *Bt;
    const float* bias;
    unsigned short* Out;
    float scale = 1.0f;
    int m0, n0, oN, biasN;
    if (mode == 0) {
        A = xt + (size_t)b * LC; Bt = wq; bias = bq; Out = qb + (size_t)b * LC;
        m0 = blockIdx.y * 128; n0 = blockIdx.x * 128; oN = C_; biasN = 1;
        scale = QSCALE;
    } else if (mode == 1) {
        A = xt + (size_t)b * LC; Bt = wk; bias = bk; Out = kb + (size_t)b * LC;
        m0 = blockIdx.y * 128; n0 = blockIdx.x * 128; oN = C_; biasN = 1;
    } else {
        A = wv; Bt = xt + (size_t)b * LC; bias = bv; Out = vb + (size_t)b * LC;
        m0 = blockIdx.x * 128; n0 = blockIdx.y * 128; oN = L_; biasN = 0;
    }
    const int doswz = (mode != 0);

    const int t = threadIdx.x;
    const int lane = t & 63, wid = t >> 6;
    const int wm = (wid >> 1) * 64, wn = (wid & 1) * 64;
    const int q16 = lane & 15, g = lane >> 4;

    // glds staging: wave wid covers rows [wid*32, wid*32+32), 2 calls/operand
    const int gr = wid * 32 + (lane >> 2);
    const int gc = (lane & 3) * 8;
    const unsigned short* Ap0 = A  + (size_t)(m0 + gr) * C_ + gc;
    const unsigned short* Ap1 = Ap0 + 16 * C_;
    const unsigned short* Bp0 = Bt + (size_t)(n0 + gr) * C_ + gc;
    const unsigned short* Bp1 = Bp0 + 16 * C_;

    f32x4 zero4 = {0.f, 0.f, 0.f, 0.f};
    f32x4 acc[4][4];
    #pragma unroll
    for (int i = 0; i < 4; ++i)
        #pragma unroll
        for (int j = 0; j < 4; ++j) acc[i][j] = zero4;

    // prologue: stage k-step 0 into buf 0
    glds16(Ap0, &As[0][wid * 32][0]);      glds16(Ap1, &As[0][wid * 32 + 16][0]);
    glds16(Bp0, &Bs[0][wid * 32][0]);      glds16(Bp1, &Bs[0][wid * 32 + 16][0]);
    __syncthreads();

    #pragma unroll 2
    for (int it = 0; it < 16; ++it) {
        const int cur = it & 1;
        if (it < 15) {
            const int ko = (it + 1) * 32;
            glds16(Ap0 + ko, &As[cur ^ 1][wid * 32][0]);
            glds16(Ap1 + ko, &As[cur ^ 1][wid * 32 + 16][0]);
            glds16(Bp0 + ko, &Bs[cur ^ 1][wid * 32][0]);
            glds16(Bp1 + ko, &Bs[cur ^ 1][wid * 32 + 16][0]);
        }
        bf16x8 af[4], bfr[4];
        #pragma unroll
        for (int i = 0; i < 4; ++i) af[i]  = frag_ld(&As[cur][wm + 16 * i + q16][8 * g]);
        #pragma unroll
        for (int j = 0; j < 4; ++j) bfr[j] = frag_ld(&Bs[cur][wn + 16 * j + q16][8 * g]);
        #pragma unroll
        for (int i = 0; i < 4; ++i)
            #pragma unroll
            for (int j = 0; j < 4; ++j)
                acc[i][j] = __builtin_amdgcn_mfma_f32_16x16x32_bf16(
                    af[i], bfr[j], acc[i][j], 0, 0, 0);
        __syncthreads();
    }

    #pragma unroll
    for (int j = 0; j < 4; ++j) {
        const int n = n0 + wn + 16 * j + q16;
        const float bn = biasN ? bias[n] : 0.f;
        #pragma unroll
        for (int i = 0; i < 4; ++i) {
            #pragma unroll
            for (int r = 0; r < 4; ++r) {
                const int m = m0 + wm + 16 * i + 4 * g + r;
                const float v = acc[i][j][r] + (biasN ? bn : bias[m]);
                const int nn = doswz ? (n ^ ((m & 7) << 3)) : n;
                Out[(size_t)m * oN + nn] = f2bf_hw(v * scale);
            }
        }
    }
}

// =====================================================================
// gemm_out: out(B,C,L) f32 = Wo @ att^T + bo + x  (reg-prefetch staging)
// =====================================================================
__global__ __launch_bounds__(256) void gemm_out(
    const unsigned short* __restrict__ A,
    const unsigned short* __restrict__ Bt,
    const float* __restrict__ bias,
    float* __restrict__ Out, const float* __restrict__ resid)
{
    __shared__ unsigned short As[128][40];
    __shared__ unsigned short Bs[128][40];

    const int bz = blockIdx.z;
    const size_t LC = (size_t)L_ * C_;
    Bt    += (size_t)bz * LC;
    Out   += (size_t)bz * LC;
    resid += (size_t)bz * LC;

    const int n0 = blockIdx.x * 128;   // l
    const int m0 = blockIdx.y * 128;   // co
    const int t  = threadIdx.x;
    const int lane = t & 63, wid = t >> 6;
    const int wm = (wid >> 1) * 64, wn = (wid & 1) * 64;
    const int q16 = lane & 15, g = lane >> 4;

    const int srow = t >> 1;
    const int scol = (t & 1) * 16;
    const unsigned short* Ap = A  + (size_t)(m0 + srow) * C_ + scol;
    const unsigned short* Bp = Bt + (size_t)(n0 + srow) * C_ + scol;

    f32x4 zero4 = {0.f, 0.f, 0.f, 0.f};
    f32x4 acc[4][4];
    #pragma unroll
    for (int i = 0; i < 4; ++i)
        #pragma unroll
        for (int j = 0; j < 4; ++j) acc[i][j] = zero4;

    uint4 ar0 = *reinterpret_cast<const uint4*>(Ap);
    uint4 ar1 = *reinterpret_cast<const uint4*>(Ap + 8);
    uint4 br0 = *reinterpret_cast<const uint4*>(Bp);
    uint4 br1 = *reinterpret_cast<const uint4*>(Bp + 8);

    for (int k0 = 0; k0 < C_; k0 += 32) {
        __syncthreads();
        *reinterpret_cast<uint4*>(&As[srow][scol])     = ar0;
        *reinterpret_cast<uint4*>(&As[srow][scol + 8]) = ar1;
        *reinterpret_cast<uint4*>(&Bs[srow][scol])     = br0;
        *reinterpret_cast<uint4*>(&Bs[srow][scol + 8]) = br1;
        __syncthreads();
        if (k0 + 32 < C_) {
            ar0 = *reinterpret_cast<const uint4*>(Ap + k0 + 32);
            ar1 = *reinterpret_cast<const uint4*>(Ap + k0 + 40);
            br0 = *reinterpret_cast<const uint4*>(Bp + k0 + 32);
            br1 = *reinterpret_cast<const uint4*>(Bp + k0 + 40);
        }
        bf16x8 af[4], bfr[4];
        #pragma unroll
        for (int i = 0; i < 4; ++i) af[i]  = frag_ld(&As[wm + 16 * i + q16][8 * g]);
        #pragma unroll
        for (int j = 0; j < 4; ++j) bfr[j] = frag_ld(&Bs[wn + 16 * j + q16][8 * g]);
        #pragma unroll
        for (int i = 0; i < 4; ++i)
            #pragma unroll
            for (int j = 0; j < 4; ++j)
                acc[i][j] = __builtin_amdgcn_mfma_f32_16x16x32_bf16(
                    af[i], bfr[j], acc[i][j], 0, 0, 0);
    }

    #pragma unroll
    for (int j = 0; j < 4; ++j) {
        const int n = n0 + wn + 16 * j + q16;
        #pragma unroll
        for (int i = 0; i < 4; ++i) {
            #pragma unroll
            for (int r = 0; r < 4; ++r) {
                const int m = m0 + wm + 16 * i + 4 * g + r;
                const size_t off = (size_t)m * L_ + n;
                Out[off] = acc[i][j][r] + bias[m] + resid[off];
            }
        }
    }
}

// =====================================================================
// attn_mfma: flash attention. K/V staged via global_load_lds into
// double-buffered unpadded [64][64] tiles (global data pre-swizzled by
// qkv_gemm: col ^= (row&7)<<3). One barrier per k-tile (2-phase).
// Row-sum via ones-column MFMA (lacc). Swapped QK^T, exp2 softmax.
// =====================================================================
__global__ __launch_bounds__(256) void attn_mfma(
    const unsigned short* __restrict__ Qb,
    const unsigned short* __restrict__ Kb,
    const unsigned short* __restrict__ Vb,
    unsigned short* __restrict__ Ab)
{
    __shared__ unsigned short Ks[2][64][64];   // [buf][k][d]  (swizzled cols)
    __shared__ unsigned short Vs[2][64][64];   // [buf][d][k]  (swizzled cols)
    __shared__ unsigned short Pw[4][16][64];   // wave-private P (word-XOR swz)

    const int q0 = blockIdx.x * 64;
    const int h  = blockIdx.y;
    const int b  = blockIdx.z;
    const int t  = threadIdx.x, lane = t & 63, wid = t >> 6;
    const int q16 = lane & 15, g = lane >> 4;
    const int swz = (q16 & 7) << 3;   // short-offset XOR for K/V frag reads
    const int h4  = (q16 & 7) << 2;   // word-offset XOR for P

    const unsigned short* Qg = Qb + (size_t)b * L_ * C_;
    const unsigned short* Kg = Kb + (size_t)b * L_ * C_ + h * D_;
    const unsigned short* Vg = Vb + ((size_t)b * C_ + h * D_) * L_;
    unsigned short* Ag       = Ab + (size_t)b * L_ * C_;

    unsigned* pw = reinterpret_cast<unsigned*>(&Pw[wid][q16][0]);

    // Q fragments (held in registers for whole block)
    bf16x8 qf[2];
    {
        const unsigned short* qp =
            Qg + (size_t)(q0 + 16 * wid + q16) * C_ + h * D_ + 8 * g;
        qf[0] = frag_ld(qp);
        qf[1] = frag_ld(qp + 32);
    }

    // constant ones B-frag: lane q16==0 holds bf16(1.0) x8, others 0
    const unsigned ow = (q16 == 0) ? 0x3F803F80u : 0u;
    const uint4 ov = make_uint4(ow, ow, ow, ow);
    const bf16x8 onesf = __builtin_bit_cast(bf16x8, ov);

    f32x4 zero4 = {0.f, 0.f, 0.f, 0.f};
    f32x4 oacc[4], lacc = zero4;
    #pragma unroll
    for (int n = 0; n < 4; ++n) oacc[n] = zero4;
    float m_s = -INFINITY;   // running max for q-row q16 (exp2 domain)

    // glds lane mapping: 1 call = 1KB = 8 rows of 128B
    const int gr8 = lane >> 3;
    const int gc8 = (lane & 7) * 8;
    const unsigned short* Kp0 = Kg + (size_t)(16 * wid     + gr8) * C_ + gc8;
    const unsigned short* Kp1 = Kg + (size_t)(16 * wid + 8 + gr8) * C_ + gc8;
    const unsigned short* Vp0 = Vg + (size_t)(16 * wid     + gr8) * L_ + gc8;
    const unsigned short* Vp1 = Vg + (size_t)(16 * wid + 8 + gr8) * L_ + gc8;

    // prologue: stage tile 0 -> buf 0
    glds16(Kp0, &Ks[0][16 * wid][0]);
    glds16(Kp1, &Ks[0][16 * wid + 8][0]);
    glds16(Vp0, &Vs[0][16 * wid][0]);
    glds16(Vp1, &Vs[0][16 * wid + 8][0]);
    __syncthreads();

    #pragma unroll 2
    for (int kt = 0; kt < 32; ++kt) {
        const int cur = kt & 1;
        if (kt < 31) {   // issue next tile's staging early (hides under compute)
            const size_t ko = (size_t)(kt + 1) * 64;
            glds16(Kp0 + ko * C_, &Ks[cur ^ 1][16 * wid][0]);
            glds16(Kp1 + ko * C_, &Ks[cur ^ 1][16 * wid + 8][0]);
            glds16(Vp0 + ko,      &Vs[cur ^ 1][16 * wid][0]);
            glds16(Vp1 + ko,      &Vs[cur ^ 1][16 * wid + 8][0]);
        }

        // ---- S^T = K Q^T : sacc[f][r] = S[k=16f+4g+r][q=q16] ----
        f32x4 sacc[4];
        #pragma unroll
        for (int f = 0; f < 4; ++f) sacc[f] = zero4;
        #pragma unroll
        for (int s = 0; s < 2; ++s) {
            #pragma unroll
            for (int f = 0; f < 4; ++f) {
                bf16x8 kf = frag_ld(&Ks[cur][16 * f + q16][(32 * s + 8 * g) ^ swz]);
                sacc[f] = __builtin_amdgcn_mfma_f32_16x16x32_bf16(
                    kf, qf[s], sacc[f], 0, 0, 0);
            }
        }

        // ---- tile max (v_max3 tree) + 2 shfl ----
        const float t0 = fmax3(sacc[0][0], sacc[0][1], sacc[0][2]);
        const float t1 = fmax3(sacc[0][3], sacc[1][0], sacc[1][1]);
        const float t2 = fmax3(sacc[1][2], sacc[1][3], sacc[2][0]);
        const float t3 = fmax3(sacc[2][1], sacc[2][2], sacc[2][3]);
        const float t4 = fmax3(sacc[3][0], sacc[3][1], sacc[3][2]);
        float pm = fmaxf(fmax3(t0, t1, t2), fmax3(t3, t4, sacc[3][3]));
        pm = fmaxf(pm, __shfl_xor(pm, 16));
        pm = fmaxf(pm, __shfl_xor(pm, 32));

        // ---- defer-max rescale (incl. lacc) ----
        if (!__all(pm - m_s <= DEFER_THR)) {
            const float mn   = fmaxf(m_s, pm);
            const float corr = exp2f(m_s - mn);
            m_s = mn;
            #pragma unroll
            for (int r = 0; r < 4; ++r) {
                const float c_o = __shfl(corr, 20 * g + r);
                #pragma unroll
                for (int n = 0; n < 4; ++n) oacc[n][r] *= c_o;
                lacc[r] *= c_o;
            }
        }

        // ---- exp2 ----
        float p[4][4];
        #pragma unroll
        for (int f = 0; f < 4; ++f)
            #pragma unroll
            for (int r = 0; r < 4; ++r) p[f][r] = exp2f(sacc[f][r] - m_s);

        // ---- P store: hw pack + XOR-swizzled uint2 ----
        #pragma unroll
        for (int f = 0; f < 4; ++f) {
            uint2 v2;
            v2.x = cvt_pk(p[f][0], p[f][1]);
            v2.y = cvt_pk(p[f][2], p[f][3]);
            *reinterpret_cast<uint2*>(pw + ((8 * f + 2 * g) ^ h4)) = v2;
        }

        // ---- O += P V, l += P 1 (wave-private P, no barrier) ----
        #pragma unroll
        for (int s2 = 0; s2 < 2; ++s2) {
            bf16x8 pf = frag_ld(reinterpret_cast<const unsigned short*>(
                pw + ((16 * s2 + 4 * g) ^ h4)));
            #pragma unroll
            for (int n = 0; n < 4; ++n) {
                bf16x8 vf = frag_ld(&Vs[cur][16 * n + q16][(32 * s2 + 8 * g) ^ swz]);
                oacc[n] = __builtin_amdgcn_mfma_f32_16x16x32_bf16(
                    pf, vf, oacc[n], 0, 0, 0);
            }
            lacc = __builtin_amdgcn_mfma_f32_16x16x32_bf16(
                pf, onesf, lacc, 0, 0, 0);
        }

        __syncthreads();   // next tile staged (vmcnt drained) + reads done
    }

    // ---- epilogue: l from lacc col 0 (lane 16g), normalize, store ----
    #pragma unroll
    for (int r = 0; r < 4; ++r) {
        const float l_o = __shfl(lacc[r], lane & 48);
        const float inv = 1.f / l_o;
        const int q = q0 + 16 * wid + 4 * g + r;
        #pragma unroll
        for (int n = 0; n < 4; ++n)
            Ag[(size_t)q * C_ + h * D_ + 16 * n + q16] = f2bf_hw(oacc[n][r] * inv);
    }
}

// =====================================================================
extern "C" void kernel_launch(void* const* d_in, const int* in_sizes, int n_in,
                              void* d_out, int out_size, void* d_ws, size_t ws_size,
                              hipStream_t stream)
{
    const float* x  = (const float*)d_in[0];
    const float* Wq = (const float*)d_in[1];
    const float* bq = (const float*)d_in[2];
    const float* Wk = (const float*)d_in[3];
    const float* bk = (const float*)d_in[4];
    const float* Wv = (const float*)d_in[5];
    const float* bv = (const float*)d_in[6];
    const float* Wo = (const float*)d_in[7];
    const float* bo = (const float*)d_in[8];
    float* out = (float*)d_out;

    const size_t NB = (size_t)B_ * L_ * C_;
    const size_t NW = (size_t)C_ * C_;
    unsigned short* ws16 = (unsigned short*)d_ws;
    unsigned short* xt  = ws16;
    unsigned short* qb  = xt  + NB;
    unsigned short* kb  = qb  + NB;
    unsigned short* vb  = kb  + NB;
    unsigned short* att = vb  + NB;
    unsigned short* wqb = att + NB;
    unsigned short* wkb = wqb + NW;
    unsigned short* wvb = wkb + NW;
    unsigned short* wob = wvb + NW;

    prep<<<dim3(32, 8, 2 * B_), 256, 0, stream>>>(
        x, Wq, Wk, Wv, Wo, xt, wqb, wkb, wvb, wob);

    qkv_gemm<<<dim3(4, 16, 3 * B_), 256, 0, stream>>>(
        xt, wqb, wkb, wvb, bq, bk, bv, qb, kb, vb);

    attn_mfma<<<dim3(L_ / 64, H_, B_), 256, 0, stream>>>(qb, kb, vb, att);

    gemm_out<<<dim3(16, 4, B_), 256, 0, stream>>>(wob, att, bo, out, x);
}

// Round 7
// 208.556 us; speedup vs baseline: 1.0795x; 1.0795x over previous
//
#include <hip/hip_runtime.h>
#include <math.h>

#define B_ 4
#define C_ 512
#define L_ 2048
#define H_ 8
#define D_ 64
// 0.125 * log2(e): folded into Q so softmax uses exp2 (raw v_exp_f32)
#define QSCALE 0.18033688011112042f
#define DEFER_THR 12.0f

typedef __bf16 bf16x8 __attribute__((ext_vector_type(8)));
typedef float f32x4 __attribute__((ext_vector_type(4)));
typedef float f32x16 __attribute__((ext_vector_type(16)));

__device__ __forceinline__ unsigned cvt_pk(float lo, float hi) {
    unsigned r;
    asm("v_cvt_pk_bf16_f32 %0, %1, %2" : "=v"(r) : "v"(lo), "v"(hi));
    return r;
}
__device__ __forceinline__ unsigned short f2bf_hw(float a) {
    unsigned r;
    asm("v_cvt_pk_bf16_f32 %0, %1, %1" : "=v"(r) : "v"(a));
    return (unsigned short)r;
}
__device__ __forceinline__ bf16x8 frag_ld(const unsigned short* p) {
    uint4 v = *reinterpret_cast<const uint4*>(p);
    return __builtin_bit_cast(bf16x8, v);
}
__device__ __forceinline__ float fmax3(float a, float b, float c) {
    return fmaxf(fmaxf(a, b), c);   // clang fuses to v_max3_f32
}
// async global->LDS, 16B per lane; LDS dest = wave-uniform base + lane*16
__device__ __forceinline__ void glds16(const void* g, void* l) {
    __builtin_amdgcn_global_load_lds(
        (const __attribute__((address_space(1))) void*)g,
        (__attribute__((address_space(3))) void*)l, 16, 0, 0);
}

// =====================================================================
// prep: z<4  -> transpose x (B,C,L) f32 -> xt (B,L,C) bf16 (64x64 tiles)
//       z>=4 -> convert weight matrix (z-4) f32 -> bf16
// =====================================================================
__global__ __launch_bounds__(256) void prep(
    const float* __restrict__ x,
    const float* __restrict__ w0, const float* __restrict__ w1,
    const float* __restrict__ w2, const float* __restrict__ w3,
    unsigned short* __restrict__ xt,
    unsigned short* __restrict__ o0, unsigned short* __restrict__ o1,
    unsigned short* __restrict__ o2, unsigned short* __restrict__ o3)
{
    __shared__ float T[64][68];
    const int t = threadIdx.x;

    if (blockIdx.z < B_) {
        const int b  = blockIdx.z;
        const int l0 = blockIdx.x * 64;
        const int c0 = blockIdx.y * 64;
        const float* xb = x + (size_t)b * C_ * L_;
        unsigned short* xtb = xt + (size_t)b * L_ * C_;

        #pragma unroll
        for (int p = 0; p < 4; ++p) {
            const int ci = 16 * p + (t >> 4);
            const int l4 = (t & 15) * 4;
            *reinterpret_cast<float4*>(&T[ci][l4]) =
                *reinterpret_cast<const float4*>(xb + (size_t)(c0 + ci) * L_ + l0 + l4);
        }
        __syncthreads();

        const int lo = t >> 2;
        const int cb = (t & 3) * 16;
        unsigned w[8];
        #pragma unroll
        for (int k = 0; k < 8; ++k)
            w[k] = cvt_pk(T[cb + 2 * k][lo], T[cb + 2 * k + 1][lo]);
        unsigned short* dst = xtb + (size_t)(l0 + lo) * C_ + c0 + cb;
        *reinterpret_cast<uint4*>(dst)     = make_uint4(w[0], w[1], w[2], w[3]);
        *reinterpret_cast<uint4*>(dst + 8) = make_uint4(w[4], w[5], w[6], w[7]);
    } else {
        const int m = blockIdx.z - B_;
        const float* src; unsigned short* dst;
        if      (m == 0) { src = w0; dst = o0; }
        else if (m == 1) { src = w1; dst = o1; }
        else if (m == 2) { src = w2; dst = o2; }
        else             { src = w3; dst = o3; }
        const int flat = blockIdx.x + 32 * blockIdx.y;   // 0..255
        const size_t idx = ((size_t)flat * 256 + t) * 4;
        const float4 v = *reinterpret_cast<const float4*>(src + idx);
        *reinterpret_cast<uint2*>(dst + idx) =
            make_uint2(cvt_pk(v.x, v.y), cvt_pk(v.z, v.w));
    }
}

// =====================================================================
// qkv_gemm: fused Q/K/V projections, 2-phase glds double-buffer.
// mode 0: qb[l][c] = (xt Wq^T + bq) * QSCALE           (unswizzled)
// mode 1: kb[l][c] =  xt Wk^T + bk   (stored with n ^= (m&7)<<3 swizzle)
// mode 2: vb[c][l] =  Wv xt^T + bv   (stored with n ^= (m&7)<<3 swizzle)
// =====================================================================
__global__ __launch_bounds__(256) void qkv_gemm(
    const unsigned short* __restrict__ xt,
    const unsigned short* __restrict__ wq, const unsigned short* __restrict__ wk,
    const unsigned short* __restrict__ wv,
    const float* __restrict__ bq, const float* __restrict__ bk,
    const float* __restrict__ bv,
    unsigned short* __restrict__ qb, unsigned short* __restrict__ kb,
    unsigned short* __restrict__ vb)
{
    __shared__ unsigned short As[2][128][32];
    __shared__ unsigned short Bs[2][128][32];

    const int mode = blockIdx.z >> 2;
    const int b    = blockIdx.z & 3;
    const size_t LC = (size_t)L_ * C_;

    const unsigned short *A, *Bt;
    const float* bias;
    unsigned short* Out;
    float scale = 1.0f;
    int m0, n0, oN, biasN;
    if (mode == 0) {
        A = xt + (size_t)b * LC; Bt = wq; bias = bq; Out = qb + (size_t)b * LC;
        m0 = blockIdx.y * 128; n0 = blockIdx.x * 128; oN = C_; biasN = 1;
        scale = QSCALE;
    } else if (mode == 1) {
        A = xt + (size_t)b * LC; Bt = wk; bias = bk; Out = kb + (size_t)b * LC;
        m0 = blockIdx.y * 128; n0 = blockIdx.x * 128; oN = C_; biasN = 1;
    } else {
        A = wv; Bt = xt + (size_t)b * LC; bias = bv; Out = vb + (size_t)b * LC;
        m0 = blockIdx.x * 128; n0 = blockIdx.y * 128; oN = L_; biasN = 0;
    }
    const int doswz = (mode != 0);

    const int t = threadIdx.x;
    const int lane = t & 63, wid = t >> 6;
    const int wm = (wid >> 1) * 64, wn = (wid & 1) * 64;
    const int q16 = lane & 15, g = lane >> 4;

    const int gr = wid * 32 + (lane >> 2);
    const int gc = (lane & 3) * 8;
    const unsigned short* Ap0 = A  + (size_t)(m0 + gr) * C_ + gc;
    const unsigned short* Ap1 = Ap0 + 16 * C_;
    const unsigned short* Bp0 = Bt + (size_t)(n0 + gr) * C_ + gc;
    const unsigned short* Bp1 = Bp0 + 16 * C_;

    f32x4 zero4 = {0.f, 0.f, 0.f, 0.f};
    f32x4 acc[4][4];
    #pragma unroll
    for (int i = 0; i < 4; ++i)
        #pragma unroll
        for (int j = 0; j < 4; ++j) acc[i][j] = zero4;

    glds16(Ap0, &As[0][wid * 32][0]);      glds16(Ap1, &As[0][wid * 32 + 16][0]);
    glds16(Bp0, &Bs[0][wid * 32][0]);      glds16(Bp1, &Bs[0][wid * 32 + 16][0]);
    __syncthreads();

    #pragma unroll 2
    for (int it = 0; it < 16; ++it) {
        const int cur = it & 1;
        if (it < 15) {
            const int ko = (it + 1) * 32;
            glds16(Ap0 + ko, &As[cur ^ 1][wid * 32][0]);
            glds16(Ap1 + ko, &As[cur ^ 1][wid * 32 + 16][0]);
            glds16(Bp0 + ko, &Bs[cur ^ 1][wid * 32][0]);
            glds16(Bp1 + ko, &Bs[cur ^ 1][wid * 32 + 16][0]);
        }
        bf16x8 af[4], bfr[4];
        #pragma unroll
        for (int i = 0; i < 4; ++i) af[i]  = frag_ld(&As[cur][wm + 16 * i + q16][8 * g]);
        #pragma unroll
        for (int j = 0; j < 4; ++j) bfr[j] = frag_ld(&Bs[cur][wn + 16 * j + q16][8 * g]);
        #pragma unroll
        for (int i = 0; i < 4; ++i)
            #pragma unroll
            for (int j = 0; j < 4; ++j)
                acc[i][j] = __builtin_amdgcn_mfma_f32_16x16x32_bf16(
                    af[i], bfr[j], acc[i][j], 0, 0, 0);
        __syncthreads();
    }

    #pragma unroll
    for (int j = 0; j < 4; ++j) {
        const int n = n0 + wn + 16 * j + q16;
        const float bn = biasN ? bias[n] : 0.f;
        #pragma unroll
        for (int i = 0; i < 4; ++i) {
            #pragma unroll
            for (int r = 0; r < 4; ++r) {
                const int m = m0 + wm + 16 * i + 4 * g + r;
                const float v = acc[i][j][r] + (biasN ? bn : bias[m]);
                const int nn = doswz ? (n ^ ((m & 7) << 3)) : n;
                Out[(size_t)m * oN + nn] = f2bf_hw(v * scale);
            }
        }
    }
}

// =====================================================================
// gemm_out: out(B,C,L) f32 = Wo @ att^T + bo + x
// (2-phase glds double-buffer, same template as qkv_gemm)
// =====================================================================
__global__ __launch_bounds__(256) void gemm_out(
    const unsigned short* __restrict__ A,
    const unsigned short* __restrict__ Bt,
    const float* __restrict__ bias,
    float* __restrict__ Out, const float* __restrict__ resid)
{
    __shared__ unsigned short As[2][128][32];
    __shared__ unsigned short Bs[2][128][32];

    const int bz = blockIdx.z;
    const size_t LC = (size_t)L_ * C_;
    Bt    += (size_t)bz * LC;
    Out   += (size_t)bz * LC;
    resid += (size_t)bz * LC;

    const int n0 = blockIdx.x * 128;   // l
    const int m0 = blockIdx.y * 128;   // co
    const int t  = threadIdx.x;
    const int lane = t & 63, wid = t >> 6;
    const int wm = (wid >> 1) * 64, wn = (wid & 1) * 64;
    const int q16 = lane & 15, g = lane >> 4;

    const int gr = wid * 32 + (lane >> 2);
    const int gc = (lane & 3) * 8;
    const unsigned short* Ap0 = A  + (size_t)(m0 + gr) * C_ + gc;
    const unsigned short* Ap1 = Ap0 + 16 * C_;
    const unsigned short* Bp0 = Bt + (size_t)(n0 + gr) * C_ + gc;
    const unsigned short* Bp1 = Bp0 + 16 * C_;

    f32x4 zero4 = {0.f, 0.f, 0.f, 0.f};
    f32x4 acc[4][4];
    #pragma unroll
    for (int i = 0; i < 4; ++i)
        #pragma unroll
        for (int j = 0; j < 4; ++j) acc[i][j] = zero4;

    glds16(Ap0, &As[0][wid * 32][0]);      glds16(Ap1, &As[0][wid * 32 + 16][0]);
    glds16(Bp0, &Bs[0][wid * 32][0]);      glds16(Bp1, &Bs[0][wid * 32 + 16][0]);
    __syncthreads();

    #pragma unroll 2
    for (int it = 0; it < 16; ++it) {
        const int cur = it & 1;
        if (it < 15) {
            const int ko = (it + 1) * 32;
            glds16(Ap0 + ko, &As[cur ^ 1][wid * 32][0]);
            glds16(Ap1 + ko, &As[cur ^ 1][wid * 32 + 16][0]);
            glds16(Bp0 + ko, &Bs[cur ^ 1][wid * 32][0]);
            glds16(Bp1 + ko, &Bs[cur ^ 1][wid * 32 + 16][0]);
        }
        bf16x8 af[4], bfr[4];
        #pragma unroll
        for (int i = 0; i < 4; ++i) af[i]  = frag_ld(&As[cur][wm + 16 * i + q16][8 * g]);
        #pragma unroll
        for (int j = 0; j < 4; ++j) bfr[j] = frag_ld(&Bs[cur][wn + 16 * j + q16][8 * g]);
        #pragma unroll
        for (int i = 0; i < 4; ++i)
            #pragma unroll
            for (int j = 0; j < 4; ++j)
                acc[i][j] = __builtin_amdgcn_mfma_f32_16x16x32_bf16(
                    af[i], bfr[j], acc[i][j], 0, 0, 0);
        __syncthreads();
    }

    #pragma unroll
    for (int j = 0; j < 4; ++j) {
        const int n = n0 + wn + 16 * j + q16;
        #pragma unroll
        for (int i = 0; i < 4; ++i) {
            #pragma unroll
            for (int r = 0; r < 4; ++r) {
                const int m = m0 + wm + 16 * i + 4 * g + r;
                const size_t off = (size_t)m * L_ + n;
                Out[off] = acc[i][j][r] + bias[m] + resid[off];
            }
        }
    }
}

// =====================================================================
// attn_mfma: 32x32x16 MFMA flash attention, fully in-register P.
// Swapped QK^T: S^T tile per wave; lane owns one q-row (q = lane&31).
// P -> PV A-frags via cvt_pk + v_permlane32_swap (no P LDS buffer).
// K/V glds double-buffered [64][64] (global pre-swizzled col^=(row&7)<<3).
// Block = (b, h, 128 q); 4 waves x 32 q. Row-sum via ones-column MFMA.
// =====================================================================
__global__ __launch_bounds__(256) void attn_mfma(
    const unsigned short* __restrict__ Qb,
    const unsigned short* __restrict__ Kb,
    const unsigned short* __restrict__ Vb,
    unsigned short* __restrict__ Ab)
{
    __shared__ unsigned short Ks[2][64][64];   // [buf][k][d]  swizzled cols
    __shared__ unsigned short Vs[2][64][64];   // [buf][d][k]  swizzled cols

    const int q0 = blockIdx.x * 128;
    const int h  = blockIdx.y;
    const int b  = blockIdx.z;
    const int t  = threadIdx.x, lane = t & 63, wid = t >> 6;
    const int q32 = lane & 31, hi = lane >> 5;
    const int swz = (q32 & 7) << 3;   // row&7 == q32&7 for all our row reads

    const unsigned short* Qg = Qb + (size_t)b * L_ * C_;
    const unsigned short* Kg = Kb + (size_t)b * L_ * C_ + h * D_;
    const unsigned short* Vg = Vb + ((size_t)b * C_ + h * D_) * L_;
    unsigned short* Ag       = Ab + (size_t)b * L_ * C_;

    // Q B-frags (col = q32, k-dim = d = 16c + 8hi + j), held all block
    bf16x8 qf[4];
    {
        const unsigned short* qp =
            Qg + (size_t)(q0 + 32 * wid + q32) * C_ + h * D_ + 8 * hi;
        #pragma unroll
        for (int c = 0; c < 4; ++c) qf[c] = frag_ld(qp + 16 * c);
    }

    // ones B-frag: column 0 of a 16x32 tile = 1.0 (lanes with q32==0)
    const unsigned ow = (q32 == 0) ? 0x3F803F80u : 0u;
    const uint4 ov = make_uint4(ow, ow, ow, ow);
    const bf16x8 onesf = __builtin_bit_cast(bf16x8, ov);

    f32x16 zero16 = {0.f,0.f,0.f,0.f,0.f,0.f,0.f,0.f,
                     0.f,0.f,0.f,0.f,0.f,0.f,0.f,0.f};
    f32x16 oacc0 = zero16, oacc1 = zero16, lacc = zero16;
    float m_s = -INFINITY;   // running max for q-row q32 (exp2 domain)

    // glds staging: wave wid covers rows [16wid, 16wid+16)
    const int gr8 = lane >> 3;
    const int gc8 = (lane & 7) * 8;
    const unsigned short* Kp0 = Kg + (size_t)(16 * wid + gr8) * C_ + gc8;
    const unsigned short* Kp1 = Kp0 + (size_t)8 * C_;
    const unsigned short* Vp0 = Vg + (size_t)(16 * wid + gr8) * L_ + gc8;
    const unsigned short* Vp1 = Vp0 + (size_t)8 * L_;

    glds16(Kp0, &Ks[0][16 * wid][0]);
    glds16(Kp1, &Ks[0][16 * wid + 8][0]);
    glds16(Vp0, &Vs[0][16 * wid][0]);
    glds16(Vp1, &Vs[0][16 * wid + 8][0]);
    __syncthreads();

    #pragma unroll 2
    for (int kt = 0; kt < 32; ++kt) {
        const int cur = kt & 1;
        if (kt < 31) {
            const size_t ko = (size_t)(kt + 1) * 64;
            glds16(Kp0 + ko * C_, &Ks[cur ^ 1][16 * wid][0]);
            glds16(Kp1 + ko * C_, &Ks[cur ^ 1][16 * wid + 8][0]);
            glds16(Vp0 + ko,      &Vs[cur ^ 1][16 * wid][0]);
            glds16(Vp1 + ko,      &Vs[cur ^ 1][16 * wid + 8][0]);
        }

        // ---- S^T = K Q^T : s0/s1 = k-halves; lane owns q = q32 ----
        f32x16 s0 = zero16, s1 = zero16;
        #pragma unroll
        for (int c = 0; c < 4; ++c) {
            const int co = (16 * c + 8 * hi) ^ swz;
            bf16x8 k0 = frag_ld(&Ks[cur][q32][co]);
            bf16x8 k1 = frag_ld(&Ks[cur][32 + q32][co]);
            s0 = __builtin_amdgcn_mfma_f32_32x32x16_bf16(k0, qf[c], s0, 0, 0, 0);
            s1 = __builtin_amdgcn_mfma_f32_32x32x16_bf16(k1, qf[c], s1, 0, 0, 0);
        }

        // ---- in-lane max over 32 values + 1 cross shfl ----
        const float a0 = fmax3(s0[0], s0[1], s0[2]);
        const float a1 = fmax3(s0[3], s0[4], s0[5]);
        const float a2 = fmax3(s0[6], s0[7], s0[8]);
        const float a3 = fmax3(s0[9], s0[10], s0[11]);
        const float a4 = fmax3(s0[12], s0[13], s0[14]);
        const float a5 = fmax3(s0[15], s1[0], s1[1]);
        const float a6 = fmax3(s1[2], s1[3], s1[4]);
        const float a7 = fmax3(s1[5], s1[6], s1[7]);
        const float a8 = fmax3(s1[8], s1[9], s1[10]);
        const float a9 = fmax3(s1[11], s1[12], s1[13]);
        const float b0 = fmax3(a0, a1, a2);
        const float b1 = fmax3(a3, a4, a5);
        const float b2 = fmax3(a6, a7, a8);
        const float b3 = fmax3(a9, s1[14], s1[15]);
        float pm = fmaxf(fmaxf(b0, b1), fmaxf(b2, b3));
        pm = fmaxf(pm, __shfl_xor(pm, 32));

        // ---- defer-max rescale (rare) ----
        if (!__all(pm - m_s <= DEFER_THR)) {
            const float mn   = fmaxf(m_s, pm);
            const float corr = exp2f(m_s - mn);
            m_s = mn;
            #pragma unroll
            for (int r = 0; r < 16; ++r) {
                const float cr = __shfl(corr, (r & 3) + 8 * (r >> 2) + 4 * hi);
                oacc0[r] *= cr; oacc1[r] *= cr; lacc[r] *= cr;
            }
        }

        // ---- exp2 (all 32 values are row q32: m_s is lane-local) ----
        float p0[16], p1[16];
        #pragma unroll
        for (int r = 0; r < 16; ++r) {
            p0[r] = exp2f(s0[r] - m_s);
            p1[r] = exp2f(s1[r] - m_s);
        }

        // ---- pack P -> A-frags (cvt_pk + permlane32_swap), PV, l-sum ----
        #pragma unroll
        for (int ks = 0; ks < 4; ++ks) {
            const int rb = 8 * (ks & 1);
            #define PPX(i) ((ks < 2) ? p0[(i)] : p1[(i)])
            unsigned wa = cvt_pk(PPX(rb + 0), PPX(rb + 1));
            unsigned wb = cvt_pk(PPX(rb + 2), PPX(rb + 3));
            unsigned wc = cvt_pk(PPX(rb + 4), PPX(rb + 5));
            unsigned wd = cvt_pk(PPX(rb + 6), PPX(rb + 7));
            #undef PPX
            asm volatile("v_permlane32_swap_b32 %0, %1" : "+v"(wa), "+v"(wc));
            asm volatile("v_permlane32_swap_b32 %0, %1" : "+v"(wb), "+v"(wd));
            const uint4 pv = make_uint4(wa, wb, wc, wd);
            const bf16x8 paf = __builtin_bit_cast(bf16x8, pv);

            const int co = (16 * ks + 8 * hi) ^ swz;
            bf16x8 v0 = frag_ld(&Vs[cur][q32][co]);
            bf16x8 v1 = frag_ld(&Vs[cur][32 + q32][co]);
            oacc0 = __builtin_amdgcn_mfma_f32_32x32x16_bf16(paf, v0, oacc0, 0, 0, 0);
            oacc1 = __builtin_amdgcn_mfma_f32_32x32x16_bf16(paf, v1, oacc1, 0, 0, 0);
            lacc  = __builtin_amdgcn_mfma_f32_32x32x16_bf16(paf, onesf, lacc, 0, 0, 0);
        }

        __syncthreads();   // next tile staged (vmcnt drained) + reads done
    }

    // ---- epilogue: l lives in lacc col 0 (lanes 0/32), normalize, store ----
    #pragma unroll
    for (int r = 0; r < 16; ++r) {
        const float lv  = __shfl(lacc[r], hi << 5);
        const float inv = 1.f / lv;
        const int q = q0 + 32 * wid + (r & 3) + 8 * (r >> 2) + 4 * hi;
        unsigned short* op = Ag + (size_t)q * C_ + h * D_ + q32;
        op[0]  = f2bf_hw(oacc0[r] * inv);
        op[32] = f2bf_hw(oacc1[r] * inv);
    }
}

// =====================================================================
extern "C" void kernel_launch(void* const* d_in, const int* in_sizes, int n_in,
                              void* d_out, int out_size, void* d_ws, size_t ws_size,
                              hipStream_t stream)
{
    const float* x  = (const float*)d_in[0];
    const float* Wq = (const float*)d_in[1];
    const float* bq = (const float*)d_in[2];
    const float* Wk = (const float*)d_in[3];
    const float* bk = (const float*)d_in[4];
    const float* Wv = (const float*)d_in[5];
    const float* bv = (const float*)d_in[6];
    const float* Wo = (const float*)d_in[7];
    const float* bo = (const float*)d_in[8];
    float* out = (float*)d_out;

    const size_t NB = (size_t)B_ * L_ * C_;
    const size_t NW = (size_t)C_ * C_;
    unsigned short* ws16 = (unsigned short*)d_ws;
    unsigned short* xt  = ws16;
    unsigned short* qb  = xt  + NB;
    unsigned short* kb  = qb  + NB;
    unsigned short* vb  = kb  + NB;
    unsigned short* att = vb  + NB;
    unsigned short* wqb = att + NB;
    unsigned short* wkb = wqb + NW;
    unsigned short* wvb = wkb + NW;
    unsigned short* wob = wvb + NW;

    prep<<<dim3(32, 8, 2 * B_), 256, 0, stream>>>(
        x, Wq, Wk, Wv, Wo, xt, wqb, wkb, wvb, wob);

    qkv_gemm<<<dim3(4, 16, 3 * B_), 256, 0, stream>>>(
        xt, wqb, wkb, wvb, bq, bk, bv, qb, kb, vb);

    attn_mfma<<<dim3(L_ / 128, H_, B_), 256, 0, stream>>>(qb, kb, vb, att);

    gemm_out<<<dim3(16, 4, B_), 256, 0, stream>>>(wob, att, bo, out, x);
}

// Round 9
// 200.081 us; speedup vs baseline: 1.1252x; 1.0424x over previous
//
#include <hip/hip_runtime.h>
#include <math.h>

#define B_ 4
#define C_ 512
#define L_ 2048
#define H_ 8
#define D_ 64
// 0.125 * log2(e): folded into Q so softmax uses exp2 (raw v_exp_f32)
#define QSCALE 0.18033688011112042f
#define DEFER_THR 12.0f

typedef __bf16 bf16x8 __attribute__((ext_vector_type(8)));
typedef float f32x4 __attribute__((ext_vector_type(4)));
typedef float f32x16 __attribute__((ext_vector_type(16)));

__device__ __forceinline__ unsigned cvt_pk(float lo, float hi) {
    unsigned r;
    asm("v_cvt_pk_bf16_f32 %0, %1, %2" : "=v"(r) : "v"(lo), "v"(hi));
    return r;
}
__device__ __forceinline__ unsigned short f2bf_hw(float a) {
    unsigned r;
    asm("v_cvt_pk_bf16_f32 %0, %1, %1" : "=v"(r) : "v"(a));
    return (unsigned short)r;
}
__device__ __forceinline__ bf16x8 frag_ld(const unsigned short* p) {
    uint4 v = *reinterpret_cast<const uint4*>(p);
    return __builtin_bit_cast(bf16x8, v);
}
__device__ __forceinline__ float fmax3(float a, float b, float c) {
    return fmaxf(fmaxf(a, b), c);   // clang fuses to v_max3_f32
}
// async global->LDS, 16B per lane; LDS dest = wave-uniform base + lane*16
__device__ __forceinline__ void glds16(const void* g, void* l) {
    __builtin_amdgcn_global_load_lds(
        (const __attribute__((address_space(1))) void*)g,
        (__attribute__((address_space(3))) void*)l, 16, 0, 0);
}

// =====================================================================
// prep: z<4  -> transpose x (B,C,L) f32 -> xt (B,L,C) bf16 (64x64 tiles)
//       z>=4 -> convert weight matrix (z-4) f32 -> bf16
// =====================================================================
__global__ __launch_bounds__(256) void prep(
    const float* __restrict__ x,
    const float* __restrict__ w0, const float* __restrict__ w1,
    const float* __restrict__ w2, const float* __restrict__ w3,
    unsigned short* __restrict__ xt,
    unsigned short* __restrict__ o0, unsigned short* __restrict__ o1,
    unsigned short* __restrict__ o2, unsigned short* __restrict__ o3)
{
    __shared__ float T[64][68];
    const int t = threadIdx.x;

    if (blockIdx.z < B_) {
        const int b  = blockIdx.z;
        const int l0 = blockIdx.x * 64;
        const int c0 = blockIdx.y * 64;
        const float* xb = x + (size_t)b * C_ * L_;
        unsigned short* xtb = xt + (size_t)b * L_ * C_;

        #pragma unroll
        for (int p = 0; p < 4; ++p) {
            const int ci = 16 * p + (t >> 4);
            const int l4 = (t & 15) * 4;
            *reinterpret_cast<float4*>(&T[ci][l4]) =
                *reinterpret_cast<const float4*>(xb + (size_t)(c0 + ci) * L_ + l0 + l4);
        }
        __syncthreads();

        const int lo = t >> 2;
        const int cb = (t & 3) * 16;
        unsigned w[8];
        #pragma unroll
        for (int k = 0; k < 8; ++k)
            w[k] = cvt_pk(T[cb + 2 * k][lo], T[cb + 2 * k + 1][lo]);
        unsigned short* dst = xtb + (size_t)(l0 + lo) * C_ + c0 + cb;
        *reinterpret_cast<uint4*>(dst)     = make_uint4(w[0], w[1], w[2], w[3]);
        *reinterpret_cast<uint4*>(dst + 8) = make_uint4(w[4], w[5], w[6], w[7]);
    } else {
        const int m = blockIdx.z - B_;
        const float* src; unsigned short* dst;
        if      (m == 0) { src = w0; dst = o0; }
        else if (m == 1) { src = w1; dst = o1; }
        else if (m == 2) { src = w2; dst = o2; }
        else             { src = w3; dst = o3; }
        const int flat = blockIdx.x + 32 * blockIdx.y;   // 0..255
        const size_t idx = ((size_t)flat * 256 + t) * 4;
        const float4 v = *reinterpret_cast<const float4*>(src + idx);
        *reinterpret_cast<uint2*>(dst + idx) =
            make_uint2(cvt_pk(v.x, v.y), cvt_pk(v.z, v.w));
    }
}

// =====================================================================
// qkv_gemm: fused Q/K/V projections (2-barrier single-buffer glds —
// the measured-best structure; dbuf variant regressed ~16 us).
// mode 0: qb[l][c] = (xt Wq^T + bq) * QSCALE           (unswizzled)
// mode 1: kb[l][c] =  xt Wk^T + bk   (stored with n ^= (m&7)<<3 swizzle)
// mode 2: vb[c][l] =  Wv xt^T + bv   (stored with n ^= (m&7)<<3 swizzle)
// =====================================================================
__global__ __launch_bounds__(256) void qkv_gemm(
    const unsigned short* __restrict__ xt,
    const unsigned short* __restrict__ wq, const unsigned short* __restrict__ wk,
    const unsigned short* __restrict__ wv,
    const float* __restrict__ bq, const float* __restrict__ bk,
    const float* __restrict__ bv,
    unsigned short* __restrict__ qb, unsigned short* __restrict__ kb,
    unsigned short* __restrict__ vb)
{
    __shared__ unsigned short As[128][32];
    __shared__ unsigned short Bs[128][32];

    const int mode = blockIdx.z >> 2;
    const int b    = blockIdx.z & 3;
    const size_t LC = (size_t)L_ * C_;

    const unsigned short *A, *Bt;
    const float* bias;
    unsigned short* Out;
    float scale = 1.0f;
    int m0, n0, oN, biasN;
    if (mode == 0) {
        A = xt + (size_t)b * LC; Bt = wq; bias = bq; Out = qb + (size_t)b * LC;
        m0 = blockIdx.y * 128; n0 = blockIdx.x * 128; oN = C_; biasN = 1;
        scale = QSCALE;
    } else if (mode == 1) {
        A = xt + (size_t)b * LC; Bt = wk; bias = bk; Out = kb + (size_t)b * LC;
        m0 = blockIdx.y * 128; n0 = blockIdx.x * 128; oN = C_; biasN = 1;
    } else {
        A = wv; Bt = xt + (size_t)b * LC; bias = bv; Out = vb + (size_t)b * LC;
        m0 = blockIdx.x * 128; n0 = blockIdx.y * 128; oN = L_; biasN = 0;
    }
    const int doswz = (mode != 0);

    const int t = threadIdx.x;
    const int lane = t & 63, wid = t >> 6;
    const int wm = (wid >> 1) * 64, wn = (wid & 1) * 64;
    const int q16 = lane & 15, g = lane >> 4;

    const int gr = wid * 32 + (lane >> 2);
    const int gc = (lane & 3) * 8;
    const unsigned short* Ap0 = A  + (size_t)(m0 + gr) * C_ + gc;
    const unsigned short* Ap1 = Ap0 + 16 * C_;
    const unsigned short* Bp0 = Bt + (size_t)(n0 + gr) * C_ + gc;
    const unsigned short* Bp1 = Bp0 + 16 * C_;
    unsigned short* lA0 = &As[wid * 32][0];
    unsigned short* lA1 = &As[wid * 32 + 16][0];
    unsigned short* lB0 = &Bs[wid * 32][0];
    unsigned short* lB1 = &Bs[wid * 32 + 16][0];

    f32x4 zero4 = {0.f, 0.f, 0.f, 0.f};
    f32x4 acc[4][4];
    #pragma unroll
    for (int i = 0; i < 4; ++i)
        #pragma unroll
        for (int j = 0; j < 4; ++j) acc[i][j] = zero4;

    for (int k0 = 0; k0 < C_; k0 += 32) {
        __syncthreads();                       // prev tile reads done
        glds16(Ap0 + k0, lA0); glds16(Ap1 + k0, lA1);
        glds16(Bp0 + k0, lB0); glds16(Bp1 + k0, lB1);
        __syncthreads();                       // vmcnt(0) drained before barrier
        bf16x8 af[4], bfr[4];
        #pragma unroll
        for (int i = 0; i < 4; ++i) af[i]  = frag_ld(&As[wm + 16 * i + q16][8 * g]);
        #pragma unroll
        for (int j = 0; j < 4; ++j) bfr[j] = frag_ld(&Bs[wn + 16 * j + q16][8 * g]);
        #pragma unroll
        for (int i = 0; i < 4; ++i)
            #pragma unroll
            for (int j = 0; j < 4; ++j)
                acc[i][j] = __builtin_amdgcn_mfma_f32_16x16x32_bf16(
                    af[i], bfr[j], acc[i][j], 0, 0, 0);
    }

    #pragma unroll
    for (int j = 0; j < 4; ++j) {
        const int n = n0 + wn + 16 * j + q16;
        const float bn = biasN ? bias[n] : 0.f;
        #pragma unroll
        for (int i = 0; i < 4; ++i) {
            #pragma unroll
            for (int r = 0; r < 4; ++r) {
                const int m = m0 + wm + 16 * i + 4 * g + r;
                const float v = acc[i][j][r] + (biasN ? bn : bias[m]);
                const int nn = doswz ? (n ^ ((m & 7) << 3)) : n;
                Out[(size_t)m * oN + nn] = f2bf_hw(v * scale);
            }
        }
    }
}

// =====================================================================
// gemm_out: out(B,C,L) f32 = Wo @ att^T + bo + x  (reg-prefetch staging —
// the measured-good r4 structure)
// =====================================================================
__global__ __launch_bounds__(256) void gemm_out(
    const unsigned short* __restrict__ A,
    const unsigned short* __restrict__ Bt,
    const float* __restrict__ bias,
    float* __restrict__ Out, const float* __restrict__ resid)
{
    __shared__ unsigned short As[128][40];
    __shared__ unsigned short Bs[128][40];

    const int bz = blockIdx.z;
    const size_t LC = (size_t)L_ * C_;
    Bt    += (size_t)bz * LC;
    Out   += (size_t)bz * LC;
    resid += (size_t)bz * LC;

    const int n0 = blockIdx.x * 128;   // l
    const int m0 = blockIdx.y * 128;   // co
    const int t  = threadIdx.x;
    const int lane = t & 63, wid = t >> 6;
    const int wm = (wid >> 1) * 64, wn = (wid & 1) * 64;
    const int q16 = lane & 15, g = lane >> 4;

    const int srow = t >> 1;
    const int scol = (t & 1) * 16;
    const unsigned short* Ap = A  + (size_t)(m0 + srow) * C_ + scol;
    const unsigned short* Bp = Bt + (size_t)(n0 + srow) * C_ + scol;

    f32x4 zero4 = {0.f, 0.f, 0.f, 0.f};
    f32x4 acc[4][4];
    #pragma unroll
    for (int i = 0; i < 4; ++i)
        #pragma unroll
        for (int j = 0; j < 4; ++j) acc[i][j] = zero4;

    uint4 ar0 = *reinterpret_cast<const uint4*>(Ap);
    uint4 ar1 = *reinterpret_cast<const uint4*>(Ap + 8);
    uint4 br0 = *reinterpret_cast<const uint4*>(Bp);
    uint4 br1 = *reinterpret_cast<const uint4*>(Bp + 8);

    for (int k0 = 0; k0 < C_; k0 += 32) {
        __syncthreads();
        *reinterpret_cast<uint4*>(&As[srow][scol])     = ar0;
        *reinterpret_cast<uint4*>(&As[srow][scol + 8]) = ar1;
        *reinterpret_cast<uint4*>(&Bs[srow][scol])     = br0;
        *reinterpret_cast<uint4*>(&Bs[srow][scol + 8]) = br1;
        __syncthreads();
        if (k0 + 32 < C_) {
            ar0 = *reinterpret_cast<const uint4*>(Ap + k0 + 32);
            ar1 = *reinterpret_cast<const uint4*>(Ap + k0 + 40);
            br0 = *reinterpret_cast<const uint4*>(Bp + k0 + 32);
            br1 = *reinterpret_cast<const uint4*>(Bp + k0 + 40);
        }
        bf16x8 af[4], bfr[4];
        #pragma unroll
        for (int i = 0; i < 4; ++i) af[i]  = frag_ld(&As[wm + 16 * i + q16][8 * g]);
        #pragma unroll
        for (int j = 0; j < 4; ++j) bfr[j] = frag_ld(&Bs[wn + 16 * j + q16][8 * g]);
        #pragma unroll
        for (int i = 0; i < 4; ++i)
            #pragma unroll
            for (int j = 0; j < 4; ++j)
                acc[i][j] = __builtin_amdgcn_mfma_f32_16x16x32_bf16(
                    af[i], bfr[j], acc[i][j], 0, 0, 0);
    }

    #pragma unroll
    for (int j = 0; j < 4; ++j) {
        const int n = n0 + wn + 16 * j + q16;
        #pragma unroll
        for (int i = 0; i < 4; ++i) {
            #pragma unroll
            for (int r = 0; r < 4; ++r) {
                const int m = m0 + wm + 16 * i + 4 * g + r;
                const size_t off = (size_t)m * L_ + n;
                Out[off] = acc[i][j][r] + bias[m] + resid[off];
            }
        }
    }
}

// =====================================================================
// attn_mfma: 32x32x16 MFMA flash attention, split-K x2 (flash-decoding).
// z = b*2 + half; each block does 16 of 32 KV tiles, writes UNNORMALIZED
// O-partials (f32) + per-q-row (m, l). grid 1024 -> 4 blocks/CU.
// =====================================================================
__global__ __launch_bounds__(256) void attn_mfma(
    const unsigned short* __restrict__ Qb,
    const unsigned short* __restrict__ Kb,
    const unsigned short* __restrict__ Vb,
    float* __restrict__ opart, float2* __restrict__ mlb)
{
    __shared__ unsigned short Ks[2][64][64];   // [buf][k][d]  swizzled cols
    __shared__ unsigned short Vs[2][64][64];   // [buf][d][k]  swizzled cols

    const int q0   = blockIdx.x * 128;
    const int h    = blockIdx.y;
    const int b    = blockIdx.z >> 1;
    const int half = blockIdx.z & 1;
    const int t  = threadIdx.x, lane = t & 63, wid = t >> 6;
    const int q32 = lane & 31, hi = lane >> 5;
    const int swz = (q32 & 7) << 3;

    const unsigned short* Qg = Qb + (size_t)b * L_ * C_;
    const unsigned short* Kg = Kb + (size_t)b * L_ * C_ + h * D_
                                  + (size_t)half * (L_ / 2) * C_;
    const unsigned short* Vg = Vb + ((size_t)b * C_ + h * D_) * L_
                                  + (size_t)half * (L_ / 2);

    // Q B-frags (col = q32, k-dim = d), held all block
    bf16x8 qf[4];
    {
        const unsigned short* qp =
            Qg + (size_t)(q0 + 32 * wid + q32) * C_ + h * D_ + 8 * hi;
        #pragma unroll
        for (int c = 0; c < 4; ++c) qf[c] = frag_ld(qp + 16 * c);
    }

    // ones B-frag: column 0 = 1.0 (lanes with q32==0)
    const unsigned ow = (q32 == 0) ? 0x3F803F80u : 0u;
    const uint4 ov = make_uint4(ow, ow, ow, ow);
    const bf16x8 onesf = __builtin_bit_cast(bf16x8, ov);

    f32x16 zero16 = {0.f,0.f,0.f,0.f,0.f,0.f,0.f,0.f,
                     0.f,0.f,0.f,0.f,0.f,0.f,0.f,0.f};
    f32x16 oacc0 = zero16, oacc1 = zero16, lacc = zero16;
    float m_s = -INFINITY;

    const int gr8 = lane >> 3;
    const int gc8 = (lane & 7) * 8;
    const unsigned short* Kp0 = Kg + (size_t)(16 * wid + gr8) * C_ + gc8;
    const unsigned short* Kp1 = Kp0 + (size_t)8 * C_;
    const unsigned short* Vp0 = Vg + (size_t)(16 * wid + gr8) * L_ + gc8;
    const unsigned short* Vp1 = Vp0 + (size_t)8 * L_;

    glds16(Kp0, &Ks[0][16 * wid][0]);
    glds16(Kp1, &Ks[0][16 * wid + 8][0]);
    glds16(Vp0, &Vs[0][16 * wid][0]);
    glds16(Vp1, &Vs[0][16 * wid + 8][0]);
    __syncthreads();

    #pragma unroll 2
    for (int kt = 0; kt < 16; ++kt) {
        const int cur = kt & 1;
        if (kt < 15) {
            const size_t ko = (size_t)(kt + 1) * 64;
            glds16(Kp0 + ko * C_, &Ks[cur ^ 1][16 * wid][0]);
            glds16(Kp1 + ko * C_, &Ks[cur ^ 1][16 * wid + 8][0]);
            glds16(Vp0 + ko,      &Vs[cur ^ 1][16 * wid][0]);
            glds16(Vp1 + ko,      &Vs[cur ^ 1][16 * wid + 8][0]);
        }

        // ---- S^T = K Q^T ----
        f32x16 s0 = zero16, s1 = zero16;
        #pragma unroll
        for (int c = 0; c < 4; ++c) {
            const int co = (16 * c + 8 * hi) ^ swz;
            bf16x8 k0 = frag_ld(&Ks[cur][q32][co]);
            bf16x8 k1 = frag_ld(&Ks[cur][32 + q32][co]);
            s0 = __builtin_amdgcn_mfma_f32_32x32x16_bf16(k0, qf[c], s0, 0, 0, 0);
            s1 = __builtin_amdgcn_mfma_f32_32x32x16_bf16(k1, qf[c], s1, 0, 0, 0);
        }

        // ---- in-lane max + 1 cross shfl ----
        const float a0 = fmax3(s0[0], s0[1], s0[2]);
        const float a1 = fmax3(s0[3], s0[4], s0[5]);
        const float a2 = fmax3(s0[6], s0[7], s0[8]);
        const float a3 = fmax3(s0[9], s0[10], s0[11]);
        const float a4 = fmax3(s0[12], s0[13], s0[14]);
        const float a5 = fmax3(s0[15], s1[0], s1[1]);
        const float a6 = fmax3(s1[2], s1[3], s1[4]);
        const float a7 = fmax3(s1[5], s1[6], s1[7]);
        const float a8 = fmax3(s1[8], s1[9], s1[10]);
        const float a9 = fmax3(s1[11], s1[12], s1[13]);
        const float b0 = fmax3(a0, a1, a2);
        const float b1 = fmax3(a3, a4, a5);
        const float b2 = fmax3(a6, a7, a8);
        const float b3 = fmax3(a9, s1[14], s1[15]);
        float pm = fmaxf(fmaxf(b0, b1), fmaxf(b2, b3));
        pm = fmaxf(pm, __shfl_xor(pm, 32));

        // ---- defer-max rescale (rare) ----
        if (!__all(pm - m_s <= DEFER_THR)) {
            const float mn   = fmaxf(m_s, pm);
            const float corr = exp2f(m_s - mn);
            m_s = mn;
            #pragma unroll
            for (int r = 0; r < 16; ++r) {
                const float cr = __shfl(corr, (r & 3) + 8 * (r >> 2) + 4 * hi);
                oacc0[r] *= cr; oacc1[r] *= cr; lacc[r] *= cr;
            }
        }

        // ---- exp2 ----
        float p0[16], p1[16];
        #pragma unroll
        for (int r = 0; r < 16; ++r) {
            p0[r] = exp2f(s0[r] - m_s);
            p1[r] = exp2f(s1[r] - m_s);
        }

        // ---- pack P -> A-frags (cvt_pk + permlane32_swap), PV, l-sum ----
        #pragma unroll
        for (int ks = 0; ks < 4; ++ks) {
            const int rb = 8 * (ks & 1);
            #define PPX(i) ((ks < 2) ? p0[(i)] : p1[(i)])
            unsigned wa = cvt_pk(PPX(rb + 0), PPX(rb + 1));
            unsigned wb = cvt_pk(PPX(rb + 2), PPX(rb + 3));
            unsigned wc = cvt_pk(PPX(rb + 4), PPX(rb + 5));
            unsigned wd = cvt_pk(PPX(rb + 6), PPX(rb + 7));
            #undef PPX
            asm volatile("v_permlane32_swap_b32 %0, %1" : "+v"(wa), "+v"(wc));
            asm volatile("v_permlane32_swap_b32 %0, %1" : "+v"(wb), "+v"(wd));
            const uint4 pv = make_uint4(wa, wb, wc, wd);
            const bf16x8 paf = __builtin_bit_cast(bf16x8, pv);

            const int co = (16 * ks + 8 * hi) ^ swz;
            bf16x8 v0 = frag_ld(&Vs[cur][q32][co]);
            bf16x8 v1 = frag_ld(&Vs[cur][32 + q32][co]);
            oacc0 = __builtin_amdgcn_mfma_f32_32x32x16_bf16(paf, v0, oacc0, 0, 0, 0);
            oacc1 = __builtin_amdgcn_mfma_f32_32x32x16_bf16(paf, v1, oacc1, 0, 0, 0);
            lacc  = __builtin_amdgcn_mfma_f32_32x32x16_bf16(paf, onesf, lacc, 0, 0, 0);
        }

        __syncthreads();
    }

    // ---- epilogue: store UNNORMALIZED partials + (m, l) per q-row ----
    const size_t PST = (size_t)B_ * H_ * L_ * D_;
    float* op = opart + (size_t)half * PST + ((size_t)b * H_ + h) * L_ * D_;
    float2* mlp = mlb + (size_t)half * (B_ * H_ * L_) + ((size_t)b * H_ + h) * L_;

    #pragma unroll
    for (int r = 0; r < 16; ++r) {
        const int crow = (r & 3) + 8 * (r >> 2) + 4 * hi;
        const int q = q0 + 32 * wid + crow;
        const float lv = __shfl(lacc[r], hi << 5);
        const float mo = __shfl(m_s, crow);
        float* o = op + (size_t)q * D_ + q32;
        o[0]  = oacc0[r];
        o[32] = oacc1[r];
        if (q32 == 0) mlp[q] = make_float2(mo, lv);
    }
}

// =====================================================================
// merge_halves: att[b][l][c] = bf16( (o0*w0 + o1*w1) / (l0*w0 + l1*w1) )
// w_i = 2^(m_i - max(m0,m1)). 8 d-elems per thread.
// =====================================================================
__global__ __launch_bounds__(256) void merge_halves(
    const float* __restrict__ opart, const float2* __restrict__ mlb,
    unsigned short* __restrict__ att)
{
    const size_t PST = (size_t)B_ * H_ * L_ * D_;
    const int idx = blockIdx.x * 256 + threadIdx.x;
    const int d8 = idx & 7;              // 8 groups of 8 d
    const int l  = (idx >> 3) & (L_ - 1);
    const int bh = idx >> 14;            // 0..31
    const int b  = bh >> 3, h = bh & 7;

    const size_t base = ((size_t)bh * L_ + l) * D_ + d8 * 8;
    const float4 x0 = *reinterpret_cast<const float4*>(opart + base);
    const float4 x1 = *reinterpret_cast<const float4*>(opart + base + 4);
    const float4 y0 = *reinterpret_cast<const float4*>(opart + PST + base);
    const float4 y1 = *reinterpret_cast<const float4*>(opart + PST + base + 4);

    const float2 ml0 = mlb[(size_t)bh * L_ + l];
    const float2 ml1 = mlb[(size_t)B_ * H_ * L_ + (size_t)bh * L_ + l];

    const float ms = fmaxf(ml0.x, ml1.x);
    const float w0 = exp2f(ml0.x - ms);
    const float w1 = exp2f(ml1.x - ms);
    const float inv = 1.0f / (ml0.y * w0 + ml1.y * w1);
    const float wa = w0 * inv, wb = w1 * inv;

    const float r0 = x0.x * wa + y0.x * wb;
    const float r1 = x0.y * wa + y0.y * wb;
    const float r2 = x0.z * wa + y0.z * wb;
    const float r3 = x0.w * wa + y0.w * wb;
    const float r4 = x1.x * wa + y1.x * wb;
    const float r5 = x1.y * wa + y1.y * wb;
    const float r6 = x1.z * wa + y1.z * wb;
    const float r7 = x1.w * wa + y1.w * wb;

    unsigned short* dst = att + (size_t)b * L_ * C_ + (size_t)l * C_ + h * D_ + d8 * 8;
    *reinterpret_cast<uint4*>(dst) = make_uint4(
        cvt_pk(r0, r1), cvt_pk(r2, r3), cvt_pk(r4, r5), cvt_pk(r6, r7));
}

// =====================================================================
extern "C" void kernel_launch(void* const* d_in, const int* in_sizes, int n_in,
                              void* d_out, int out_size, void* d_ws, size_t ws_size,
                              hipStream_t stream)
{
    const float* x  = (const float*)d_in[0];
    const float* Wq = (const float*)d_in[1];
    const float* bq = (const float*)d_in[2];
    const float* Wk = (const float*)d_in[3];
    const float* bk = (const float*)d_in[4];
    const float* Wv = (const float*)d_in[5];
    const float* bv = (const float*)d_in[6];
    const float* Wo = (const float*)d_in[7];
    const float* bo = (const float*)d_in[8];
    float* out = (float*)d_out;

    const size_t NB = (size_t)B_ * L_ * C_;
    const size_t NW = (size_t)C_ * C_;
    unsigned short* ws16 = (unsigned short*)d_ws;
    unsigned short* xt  = ws16;
    unsigned short* qb  = xt  + NB;
    unsigned short* kb  = qb  + NB;
    unsigned short* vb  = kb  + NB;
    unsigned short* att = vb  + NB;
    unsigned short* wqb = att + NB;
    unsigned short* wkb = wqb + NW;
    unsigned short* wvb = wkb + NW;
    unsigned short* wob = wvb + NW;
    float* opart = (float*)(wob + NW);                     // 2 x 16 MB f32
    float2* mlb  = (float2*)(opart + 2 * (size_t)B_ * H_ * L_ * D_);  // 1 MB

    prep<<<dim3(32, 8, 2 * B_), 256, 0, stream>>>(
        x, Wq, Wk, Wv, Wo, xt, wqb, wkb, wvb, wob);

    qkv_gemm<<<dim3(4, 16, 3 * B_), 256, 0, stream>>>(
        xt, wqb, wkb, wvb, bq, bk, bv, qb, kb, vb);

    attn_mfma<<<dim3(L_ / 128, H_, 2 * B_), 256, 0, stream>>>(
        qb, kb, vb, opart, mlb);

    merge_halves<<<dim3(B_ * H_ * L_ * 8 / 256), 256, 0, stream>>>(
        opart, mlb, att);

    gemm_out<<<dim3(16, 4, B_), 256, 0, stream>>>(wob, att, bo, out, x);
}

// Round 10
// 199.295 us; speedup vs baseline: 1.1296x; 1.0039x over previous
//
#include <hip/hip_runtime.h>
#include <math.h>

#define B_ 4
#define C_ 512
#define L_ 2048
#define H_ 8
#define D_ 64
// 0.125 * log2(e): folded into Q so softmax uses exp2 (raw v_exp_f32)
#define QSCALE 0.18033688011112042f
#define DEFER_THR 12.0f

typedef __bf16 bf16x8 __attribute__((ext_vector_type(8)));
typedef float f32x4 __attribute__((ext_vector_type(4)));
typedef float f32x16 __attribute__((ext_vector_type(16)));

__device__ __forceinline__ unsigned cvt_pk(float lo, float hi) {
    unsigned r;
    asm("v_cvt_pk_bf16_f32 %0, %1, %2" : "=v"(r) : "v"(lo), "v"(hi));
    return r;
}
__device__ __forceinline__ unsigned short f2bf_hw(float a) {
    unsigned r;
    asm("v_cvt_pk_bf16_f32 %0, %1, %1" : "=v"(r) : "v"(a));
    return (unsigned short)r;
}
__device__ __forceinline__ bf16x8 frag_ld(const unsigned short* p) {
    uint4 v = *reinterpret_cast<const uint4*>(p);
    return __builtin_bit_cast(bf16x8, v);
}
__device__ __forceinline__ float fmax3(float a, float b, float c) {
    return fmaxf(fmaxf(a, b), c);   // clang fuses to v_max3_f32
}
// async global->LDS, 16B per lane; LDS dest = wave-uniform base + lane*16
__device__ __forceinline__ void glds16(const void* g, void* l) {
    __builtin_amdgcn_global_load_lds(
        (const __attribute__((address_space(1))) void*)g,
        (__attribute__((address_space(3))) void*)l, 16, 0, 0);
}

// =====================================================================
// prep: z<4  -> transpose x (B,C,L) f32 -> xt (B,L,C) bf16 (64x64 tiles)
//       z>=4 -> convert weight matrix (z-4) f32 -> bf16
// LDS row stride 65: both staging writes and paired reads are 2-way
// bank aliasing (free); the old stride-68 layout was a 4-way read conflict.
// =====================================================================
__global__ __launch_bounds__(256) void prep(
    const float* __restrict__ x,
    const float* __restrict__ w0, const float* __restrict__ w1,
    const float* __restrict__ w2, const float* __restrict__ w3,
    unsigned short* __restrict__ xt,
    unsigned short* __restrict__ o0, unsigned short* __restrict__ o1,
    unsigned short* __restrict__ o2, unsigned short* __restrict__ o3)
{
    __shared__ float T[64][65];
    const int t = threadIdx.x;

    if (blockIdx.z < B_) {
        const int b  = blockIdx.z;
        const int l0 = blockIdx.x * 64;
        const int c0 = blockIdx.y * 64;
        const float* xb = x + (size_t)b * C_ * L_;
        unsigned short* xtb = xt + (size_t)b * L_ * C_;

        #pragma unroll
        for (int p = 0; p < 4; ++p) {
            const int ci = 16 * p + (t >> 4);
            const int l4 = (t & 15) * 4;
            const float4 v = *reinterpret_cast<const float4*>(
                xb + (size_t)(c0 + ci) * L_ + l0 + l4);
            T[ci][l4 + 0] = v.x; T[ci][l4 + 1] = v.y;
            T[ci][l4 + 2] = v.z; T[ci][l4 + 3] = v.w;
        }
        __syncthreads();

        const int lo = t >> 2;
        const int cb = (t & 3) * 16;
        unsigned w[8];
        #pragma unroll
        for (int k = 0; k < 8; ++k)
            w[k] = cvt_pk(T[cb + 2 * k][lo], T[cb + 2 * k + 1][lo]);
        unsigned short* dst = xtb + (size_t)(l0 + lo) * C_ + c0 + cb;
        *reinterpret_cast<uint4*>(dst)     = make_uint4(w[0], w[1], w[2], w[3]);
        *reinterpret_cast<uint4*>(dst + 8) = make_uint4(w[4], w[5], w[6], w[7]);
    } else {
        const int m = blockIdx.z - B_;
        const float* src; unsigned short* dst;
        if      (m == 0) { src = w0; dst = o0; }
        else if (m == 1) { src = w1; dst = o1; }
        else if (m == 2) { src = w2; dst = o2; }
        else             { src = w3; dst = o3; }
        const int flat = blockIdx.x + 32 * blockIdx.y;   // 0..255
        const size_t idx = ((size_t)flat * 256 + t) * 4;
        const float4 v = *reinterpret_cast<const float4*>(src + idx);
        *reinterpret_cast<uint2*>(dst + idx) =
            make_uint2(cvt_pk(v.x, v.y), cvt_pk(v.z, v.w));
    }
}

// =====================================================================
// qkv_gemm: fused Q/K/V projections (2-barrier single-buffer glds —
// the measured-best structure).
// mode 0: qb[l][c] = (xt Wq^T + bq) * QSCALE           (unswizzled)
// mode 1: kb[l][c] =  xt Wk^T + bk   (stored with n ^= (m&7)<<3 swizzle)
// mode 2: vb[c][l] =  Wv xt^T + bv   (stored with n ^= (m&7)<<3 swizzle)
// =====================================================================
__global__ __launch_bounds__(256) void qkv_gemm(
    const unsigned short* __restrict__ xt,
    const unsigned short* __restrict__ wq, const unsigned short* __restrict__ wk,
    const unsigned short* __restrict__ wv,
    const float* __restrict__ bq, const float* __restrict__ bk,
    const float* __restrict__ bv,
    unsigned short* __restrict__ qb, unsigned short* __restrict__ kb,
    unsigned short* __restrict__ vb)
{
    __shared__ unsigned short As[128][32];
    __shared__ unsigned short Bs[128][32];

    const int mode = blockIdx.z >> 2;
    const int b    = blockIdx.z & 3;
    const size_t LC = (size_t)L_ * C_;

    const unsigned short *A, *Bt;
    const float* bias;
    unsigned short* Out;
    float scale = 1.0f;
    int m0, n0, oN, biasN;
    if (mode == 0) {
        A = xt + (size_t)b * LC; Bt = wq; bias = bq; Out = qb + (size_t)b * LC;
        m0 = blockIdx.y * 128; n0 = blockIdx.x * 128; oN = C_; biasN = 1;
        scale = QSCALE;
    } else if (mode == 1) {
        A = xt + (size_t)b * LC; Bt = wk; bias = bk; Out = kb + (size_t)b * LC;
        m0 = blockIdx.y * 128; n0 = blockIdx.x * 128; oN = C_; biasN = 1;
    } else {
        A = wv; Bt = xt + (size_t)b * LC; bias = bv; Out = vb + (size_t)b * LC;
        m0 = blockIdx.x * 128; n0 = blockIdx.y * 128; oN = L_; biasN = 0;
    }
    const int doswz = (mode != 0);

    const int t = threadIdx.x;
    const int lane = t & 63, wid = t >> 6;
    const int wm = (wid >> 1) * 64, wn = (wid & 1) * 64;
    const int q16 = lane & 15, g = lane >> 4;

    const int gr = wid * 32 + (lane >> 2);
    const int gc = (lane & 3) * 8;
    const unsigned short* Ap0 = A  + (size_t)(m0 + gr) * C_ + gc;
    const unsigned short* Ap1 = Ap0 + 16 * C_;
    const unsigned short* Bp0 = Bt + (size_t)(n0 + gr) * C_ + gc;
    const unsigned short* Bp1 = Bp0 + 16 * C_;
    unsigned short* lA0 = &As[wid * 32][0];
    unsigned short* lA1 = &As[wid * 32 + 16][0];
    unsigned short* lB0 = &Bs[wid * 32][0];
    unsigned short* lB1 = &Bs[wid * 32 + 16][0];

    f32x4 zero4 = {0.f, 0.f, 0.f, 0.f};
    f32x4 acc[4][4];
    #pragma unroll
    for (int i = 0; i < 4; ++i)
        #pragma unroll
        for (int j = 0; j < 4; ++j) acc[i][j] = zero4;

    for (int k0 = 0; k0 < C_; k0 += 32) {
        __syncthreads();                       // prev tile reads done
        glds16(Ap0 + k0, lA0); glds16(Ap1 + k0, lA1);
        glds16(Bp0 + k0, lB0); glds16(Bp1 + k0, lB1);
        __syncthreads();                       // vmcnt(0) drained before barrier
        bf16x8 af[4], bfr[4];
        #pragma unroll
        for (int i = 0; i < 4; ++i) af[i]  = frag_ld(&As[wm + 16 * i + q16][8 * g]);
        #pragma unroll
        for (int j = 0; j < 4; ++j) bfr[j] = frag_ld(&Bs[wn + 16 * j + q16][8 * g]);
        #pragma unroll
        for (int i = 0; i < 4; ++i)
            #pragma unroll
            for (int j = 0; j < 4; ++j)
                acc[i][j] = __builtin_amdgcn_mfma_f32_16x16x32_bf16(
                    af[i], bfr[j], acc[i][j], 0, 0, 0);
    }

    #pragma unroll
    for (int j = 0; j < 4; ++j) {
        const int n = n0 + wn + 16 * j + q16;
        const float bn = biasN ? bias[n] : 0.f;
        #pragma unroll
        for (int i = 0; i < 4; ++i) {
            #pragma unroll
            for (int r = 0; r < 4; ++r) {
                const int m = m0 + wm + 16 * i + 4 * g + r;
                const float v = acc[i][j][r] + (biasN ? bn : bias[m]);
                const int nn = doswz ? (n ^ ((m & 7) << 3)) : n;
                Out[(size_t)m * oN + nn] = f2bf_hw(v * scale);
            }
        }
    }
}

// =====================================================================
// gemm_out: out(B,C,L) f32 = Wo @ att^T + bo + x  (reg-prefetch staging —
// the measured-good r4 structure)
// =====================================================================
__global__ __launch_bounds__(256) void gemm_out(
    const unsigned short* __restrict__ A,
    const unsigned short* __restrict__ Bt,
    const float* __restrict__ bias,
    float* __restrict__ Out, const float* __restrict__ resid)
{
    __shared__ unsigned short As[128][40];
    __shared__ unsigned short Bs[128][40];

    const int bz = blockIdx.z;
    const size_t LC = (size_t)L_ * C_;
    Bt    += (size_t)bz * LC;
    Out   += (size_t)bz * LC;
    resid += (size_t)bz * LC;

    const int n0 = blockIdx.x * 128;   // l
    const int m0 = blockIdx.y * 128;   // co
    const int t  = threadIdx.x;
    const int lane = t & 63, wid = t >> 6;
    const int wm = (wid >> 1) * 64, wn = (wid & 1) * 64;
    const int q16 = lane & 15, g = lane >> 4;

    const int srow = t >> 1;
    const int scol = (t & 1) * 16;
    const unsigned short* Ap = A  + (size_t)(m0 + srow) * C_ + scol;
    const unsigned short* Bp = Bt + (size_t)(n0 + srow) * C_ + scol;

    f32x4 zero4 = {0.f, 0.f, 0.f, 0.f};
    f32x4 acc[4][4];
    #pragma unroll
    for (int i = 0; i < 4; ++i)
        #pragma unroll
        for (int j = 0; j < 4; ++j) acc[i][j] = zero4;

    uint4 ar0 = *reinterpret_cast<const uint4*>(Ap);
    uint4 ar1 = *reinterpret_cast<const uint4*>(Ap + 8);
    uint4 br0 = *reinterpret_cast<const uint4*>(Bp);
    uint4 br1 = *reinterpret_cast<const uint4*>(Bp + 8);

    for (int k0 = 0; k0 < C_; k0 += 32) {
        __syncthreads();
        *reinterpret_cast<uint4*>(&As[srow][scol])     = ar0;
        *reinterpret_cast<uint4*>(&As[srow][scol + 8]) = ar1;
        *reinterpret_cast<uint4*>(&Bs[srow][scol])     = br0;
        *reinterpret_cast<uint4*>(&Bs[srow][scol + 8]) = br1;
        __syncthreads();
        if (k0 + 32 < C_) {
            ar0 = *reinterpret_cast<const uint4*>(Ap + k0 + 32);
            ar1 = *reinterpret_cast<const uint4*>(Ap + k0 + 40);
            br0 = *reinterpret_cast<const uint4*>(Bp + k0 + 32);
            br1 = *reinterpret_cast<const uint4*>(Bp + k0 + 40);
        }
        bf16x8 af[4], bfr[4];
        #pragma unroll
        for (int i = 0; i < 4; ++i) af[i]  = frag_ld(&As[wm + 16 * i + q16][8 * g]);
        #pragma unroll
        for (int j = 0; j < 4; ++j) bfr[j] = frag_ld(&Bs[wn + 16 * j + q16][8 * g]);
        #pragma unroll
        for (int i = 0; i < 4; ++i)
            #pragma unroll
            for (int j = 0; j < 4; ++j)
                acc[i][j] = __builtin_amdgcn_mfma_f32_16x16x32_bf16(
                    af[i], bfr[j], acc[i][j], 0, 0, 0);
    }

    #pragma unroll
    for (int j = 0; j < 4; ++j) {
        const int n = n0 + wn + 16 * j + q16;
        #pragma unroll
        for (int i = 0; i < 4; ++i) {
            #pragma unroll
            for (int r = 0; r < 4; ++r) {
                const int m = m0 + wm + 16 * i + 4 * g + r;
                const size_t off = (size_t)m * L_ + n;
                Out[off] = acc[i][j][r] + bias[m] + resid[off];
            }
        }
    }
}

// =====================================================================
// attn_mfma: 32x32x16 MFMA flash attention, single-pass (split-K reverted:
// it was perf-neutral for attn and its merge cost was pure overhead).
// In-register P via cvt_pk + permlane32_swap; packed-f32 softmax subs;
// setprio around MFMA clusters. Block = (b, h, 128 q); grid 512.
// =====================================================================
__global__ __launch_bounds__(256) void attn_mfma(
    const unsigned short* __restrict__ Qb,
    const unsigned short* __restrict__ Kb,
    const unsigned short* __restrict__ Vb,
    unsigned short* __restrict__ Ab)
{
    __shared__ unsigned short Ks[2][64][64];   // [buf][k][d]  swizzled cols
    __shared__ unsigned short Vs[2][64][64];   // [buf][d][k]  swizzled cols

    const int q0 = blockIdx.x * 128;
    const int h  = blockIdx.y;
    const int b  = blockIdx.z;
    const int t  = threadIdx.x, lane = t & 63, wid = t >> 6;
    const int q32 = lane & 31, hi = lane >> 5;
    const int swz = (q32 & 7) << 3;

    const unsigned short* Qg = Qb + (size_t)b * L_ * C_;
    const unsigned short* Kg = Kb + (size_t)b * L_ * C_ + h * D_;
    const unsigned short* Vg = Vb + ((size_t)b * C_ + h * D_) * L_;
    unsigned short* Ag       = Ab + (size_t)b * L_ * C_;

    // Q B-frags (col = q32, k-dim = d), held all block
    bf16x8 qf[4];
    {
        const unsigned short* qp =
            Qg + (size_t)(q0 + 32 * wid + q32) * C_ + h * D_ + 8 * hi;
        #pragma unroll
        for (int c = 0; c < 4; ++c) qf[c] = frag_ld(qp + 16 * c);
    }

    // ones B-frag: column 0 = 1.0 (lanes with q32==0)
    const unsigned ow = (q32 == 0) ? 0x3F803F80u : 0u;
    const uint4 ov = make_uint4(ow, ow, ow, ow);
    const bf16x8 onesf = __builtin_bit_cast(bf16x8, ov);

    f32x16 zero16 = {0.f,0.f,0.f,0.f,0.f,0.f,0.f,0.f,
                     0.f,0.f,0.f,0.f,0.f,0.f,0.f,0.f};
    f32x16 oacc0 = zero16, oacc1 = zero16, lacc = zero16;
    float m_s = -INFINITY;

    const int gr8 = lane >> 3;
    const int gc8 = (lane & 7) * 8;
    const unsigned short* Kp0 = Kg + (size_t)(16 * wid + gr8) * C_ + gc8;
    const unsigned short* Kp1 = Kp0 + (size_t)8 * C_;
    const unsigned short* Vp0 = Vg + (size_t)(16 * wid + gr8) * L_ + gc8;
    const unsigned short* Vp1 = Vp0 + (size_t)8 * L_;

    glds16(Kp0, &Ks[0][16 * wid][0]);
    glds16(Kp1, &Ks[0][16 * wid + 8][0]);
    glds16(Vp0, &Vs[0][16 * wid][0]);
    glds16(Vp1, &Vs[0][16 * wid + 8][0]);
    __syncthreads();

    #pragma unroll 2
    for (int kt = 0; kt < 32; ++kt) {
        const int cur = kt & 1;
        if (kt < 31) {   // issue next tile's staging early (hides under compute)
            const size_t ko = (size_t)(kt + 1) * 64;
            glds16(Kp0 + ko * C_, &Ks[cur ^ 1][16 * wid][0]);
            glds16(Kp1 + ko * C_, &Ks[cur ^ 1][16 * wid + 8][0]);
            glds16(Vp0 + ko,      &Vs[cur ^ 1][16 * wid][0]);
            glds16(Vp1 + ko,      &Vs[cur ^ 1][16 * wid + 8][0]);
        }

        // ---- S^T = K Q^T ----
        f32x16 s0 = zero16, s1 = zero16;
        __builtin_amdgcn_s_setprio(1);
        #pragma unroll
        for (int c = 0; c < 4; ++c) {
            const int co = (16 * c + 8 * hi) ^ swz;
            bf16x8 k0 = frag_ld(&Ks[cur][q32][co]);
            bf16x8 k1 = frag_ld(&Ks[cur][32 + q32][co]);
            s0 = __builtin_amdgcn_mfma_f32_32x32x16_bf16(k0, qf[c], s0, 0, 0, 0);
            s1 = __builtin_amdgcn_mfma_f32_32x32x16_bf16(k1, qf[c], s1, 0, 0, 0);
        }
        __builtin_amdgcn_s_setprio(0);

        // ---- in-lane max + 1 cross shfl ----
        const float a0 = fmax3(s0[0], s0[1], s0[2]);
        const float a1 = fmax3(s0[3], s0[4], s0[5]);
        const float a2 = fmax3(s0[6], s0[7], s0[8]);
        const float a3 = fmax3(s0[9], s0[10], s0[11]);
        const float a4 = fmax3(s0[12], s0[13], s0[14]);
        const float a5 = fmax3(s0[15], s1[0], s1[1]);
        const float a6 = fmax3(s1[2], s1[3], s1[4]);
        const float a7 = fmax3(s1[5], s1[6], s1[7]);
        const float a8 = fmax3(s1[8], s1[9], s1[10]);
        const float a9 = fmax3(s1[11], s1[12], s1[13]);
        const float b0 = fmax3(a0, a1, a2);
        const float b1 = fmax3(a3, a4, a5);
        const float b2 = fmax3(a6, a7, a8);
        const float b3 = fmax3(a9, s1[14], s1[15]);
        float pm = fmaxf(fmaxf(b0, b1), fmaxf(b2, b3));
        pm = fmaxf(pm, __shfl_xor(pm, 32));

        // ---- defer-max rescale (rare) ----
        if (!__all(pm - m_s <= DEFER_THR)) {
            const float mn   = fmaxf(m_s, pm);
            const float corr = exp2f(m_s - mn);
            m_s = mn;
            #pragma unroll
            for (int r = 0; r < 16; ++r) {
                const float cr = __shfl(corr, (r & 3) + 8 * (r >> 2) + 4 * hi);
                oacc0[r] *= cr; oacc1[r] *= cr; lacc[r] *= cr;
            }
        }

        // ---- packed-f32 subtract (v_pk_add), then exp2 ----
        f32x16 ms16;
        #pragma unroll
        for (int r = 0; r < 16; ++r) ms16[r] = m_s;
        const f32x16 d0 = s0 - ms16;
        const f32x16 d1 = s1 - ms16;
        float p0[16], p1[16];
        #pragma unroll
        for (int r = 0; r < 16; ++r) {
            p0[r] = exp2f(d0[r]);
            p1[r] = exp2f(d1[r]);
        }

        // ---- pack P -> A-frags (cvt_pk + permlane32_swap), PV, l-sum ----
        __builtin_amdgcn_s_setprio(1);
        #pragma unroll
        for (int ks = 0; ks < 4; ++ks) {
            const int rb = 8 * (ks & 1);
            #define PPX(i) ((ks < 2) ? p0[(i)] : p1[(i)])
            unsigned wa = cvt_pk(PPX(rb + 0), PPX(rb + 1));
            unsigned wb = cvt_pk(PPX(rb + 2), PPX(rb + 3));
            unsigned wc = cvt_pk(PPX(rb + 4), PPX(rb + 5));
            unsigned wd = cvt_pk(PPX(rb + 6), PPX(rb + 7));
            #undef PPX
            asm volatile("v_permlane32_swap_b32 %0, %1" : "+v"(wa), "+v"(wc));
            asm volatile("v_permlane32_swap_b32 %0, %1" : "+v"(wb), "+v"(wd));
            const uint4 pv = make_uint4(wa, wb, wc, wd);
            const bf16x8 paf = __builtin_bit_cast(bf16x8, pv);

            const int co = (16 * ks + 8 * hi) ^ swz;
            bf16x8 v0 = frag_ld(&Vs[cur][q32][co]);
            bf16x8 v1 = frag_ld(&Vs[cur][32 + q32][co]);
            oacc0 = __builtin_amdgcn_mfma_f32_32x32x16_bf16(paf, v0, oacc0, 0, 0, 0);
            oacc1 = __builtin_amdgcn_mfma_f32_32x32x16_bf16(paf, v1, oacc1, 0, 0, 0);
            lacc  = __builtin_amdgcn_mfma_f32_32x32x16_bf16(paf, onesf, lacc, 0, 0, 0);
        }
        __builtin_amdgcn_s_setprio(0);

        __syncthreads();   // next tile staged (vmcnt drained) + reads done
    }

    // ---- epilogue: l from lacc col 0 (lanes 0/32), normalize, store ----
    #pragma unroll
    for (int r = 0; r < 16; ++r) {
        const float lv  = __shfl(lacc[r], hi << 5);
        const float inv = 1.f / lv;
        const int q = q0 + 32 * wid + (r & 3) + 8 * (r >> 2) + 4 * hi;
        unsigned short* op = Ag + (size_t)q * C_ + h * D_ + q32;
        op[0]  = f2bf_hw(oacc0[r] * inv);
        op[32] = f2bf_hw(oacc1[r] * inv);
    }
}

// =====================================================================
extern "C" void kernel_launch(void* const* d_in, const int* in_sizes, int n_in,
                              void* d_out, int out_size, void* d_ws, size_t ws_size,
                              hipStream_t stream)
{
    const float* x  = (const float*)d_in[0];
    const float* Wq = (const float*)d_in[1];
    const float* bq = (const float*)d_in[2];
    const float* Wk = (const float*)d_in[3];
    const float* bk = (const float*)d_in[4];
    const float* Wv = (const float*)d_in[5];
    const float* bv = (const float*)d_in[6];
    const float* Wo = (const float*)d_in[7];
    const float* bo = (const float*)d_in[8];
    float* out = (float*)d_out;

    const size_t NB = (size_t)B_ * L_ * C_;
    const size_t NW = (size_t)C_ * C_;
    unsigned short* ws16 = (unsigned short*)d_ws;
    unsigned short* xt  = ws16;
    unsigned short* qb  = xt  + NB;
    unsigned short* kb  = qb  + NB;
    unsigned short* vb  = kb  + NB;
    unsigned short* att = vb  + NB;
    unsigned short* wqb = att + NB;
    unsigned short* wkb = wqb + NW;
    unsigned short* wvb = wkb + NW;
    unsigned short* wob = wvb + NW;

    prep<<<dim3(32, 8, 2 * B_), 256, 0, stream>>>(
        x, Wq, Wk, Wv, Wo, xt, wqb, wkb, wvb, wob);

    qkv_gemm<<<dim3(4, 16, 3 * B_), 256, 0, stream>>>(
        xt, wqb, wkb, wvb, bq, bk, bv, qb, kb, vb);

    attn_mfma<<<dim3(L_ / 128, H_, B_), 256, 0, stream>>>(qb, kb, vb, att);

    gemm_out<<<dim3(16, 4, B_), 256, 0, stream>>>(wob, att, bo, out, x);
}

// Round 11
// 191.382 us; speedup vs baseline: 1.1763x; 1.0413x over previous
//
#include <hip/hip_runtime.h>
#include <math.h>

#define B_ 4
#define C_ 512
#define L_ 2048
#define H_ 8
#define D_ 64
// 0.125 * log2(e): folded into Q so softmax uses exp2 (raw v_exp_f32)
#define QSCALE 0.18033688011112042f
#define DEFER_THR 12.0f

typedef __bf16 bf16x8 __attribute__((ext_vector_type(8)));
typedef float f32x4 __attribute__((ext_vector_type(4)));
typedef float f32x16 __attribute__((ext_vector_type(16)));

__device__ __forceinline__ unsigned cvt_pk(float lo, float hi) {
    unsigned r;
    asm("v_cvt_pk_bf16_f32 %0, %1, %2" : "=v"(r) : "v"(lo), "v"(hi));
    return r;
}
__device__ __forceinline__ unsigned short f2bf_hw(float a) {
    unsigned r;
    asm("v_cvt_pk_bf16_f32 %0, %1, %1" : "=v"(r) : "v"(a));
    return (unsigned short)r;
}
__device__ __forceinline__ bf16x8 frag_ld(const unsigned short* p) {
    uint4 v = *reinterpret_cast<const uint4*>(p);
    return __builtin_bit_cast(bf16x8, v);
}
__device__ __forceinline__ float fmax3(float a, float b, float c) {
    return fmaxf(fmaxf(a, b), c);   // clang fuses to v_max3_f32
}
// async global->LDS, 16B per lane; LDS dest = wave-uniform base + lane*16
__device__ __forceinline__ void glds16(const void* g, void* l) {
    __builtin_amdgcn_global_load_lds(
        (const __attribute__((address_space(1))) void*)g,
        (__attribute__((address_space(3))) void*)l, 16, 0, 0);
}

// =====================================================================
// prep: z<4  -> transpose x (B,C,L) f32 -> xt (B,L,C) bf16 (64x64 tiles)
//       z>=4 -> convert weight matrix (z-4) f32 -> bf16
// LDS row stride 65: staging writes and paired reads are 2-way (free).
// =====================================================================
__global__ __launch_bounds__(256) void prep(
    const float* __restrict__ x,
    const float* __restrict__ w0, const float* __restrict__ w1,
    const float* __restrict__ w2, const float* __restrict__ w3,
    unsigned short* __restrict__ xt,
    unsigned short* __restrict__ o0, unsigned short* __restrict__ o1,
    unsigned short* __restrict__ o2, unsigned short* __restrict__ o3)
{
    __shared__ float T[64][65];
    const int t = threadIdx.x;

    if (blockIdx.z < B_) {
        const int b  = blockIdx.z;
        const int l0 = blockIdx.x * 64;
        const int c0 = blockIdx.y * 64;
        const float* xb = x + (size_t)b * C_ * L_;
        unsigned short* xtb = xt + (size_t)b * L_ * C_;

        #pragma unroll
        for (int p = 0; p < 4; ++p) {
            const int ci = 16 * p + (t >> 4);
            const int l4 = (t & 15) * 4;
            const float4 v = *reinterpret_cast<const float4*>(
                xb + (size_t)(c0 + ci) * L_ + l0 + l4);
            T[ci][l4 + 0] = v.x; T[ci][l4 + 1] = v.y;
            T[ci][l4 + 2] = v.z; T[ci][l4 + 3] = v.w;
        }
        __syncthreads();

        const int lo = t >> 2;
        const int cb = (t & 3) * 16;
        unsigned w[8];
        #pragma unroll
        for (int k = 0; k < 8; ++k)
            w[k] = cvt_pk(T[cb + 2 * k][lo], T[cb + 2 * k + 1][lo]);
        unsigned short* dst = xtb + (size_t)(l0 + lo) * C_ + c0 + cb;
        *reinterpret_cast<uint4*>(dst)     = make_uint4(w[0], w[1], w[2], w[3]);
        *reinterpret_cast<uint4*>(dst + 8) = make_uint4(w[4], w[5], w[6], w[7]);
    } else {
        const int m = blockIdx.z - B_;
        const float* src; unsigned short* dst;
        if      (m == 0) { src = w0; dst = o0; }
        else if (m == 1) { src = w1; dst = o1; }
        else if (m == 2) { src = w2; dst = o2; }
        else             { src = w3; dst = o3; }
        const int flat = blockIdx.x + 32 * blockIdx.y;   // 0..255
        const size_t idx = ((size_t)flat * 256 + t) * 4;
        const float4 v = *reinterpret_cast<const float4*>(src + idx);
        *reinterpret_cast<uint2*>(dst + idx) =
            make_uint2(cvt_pk(v.x, v.y), cvt_pk(v.z, v.w));
    }
}

// =====================================================================
// qkv_gemm: fused Q/K/V projections (2-barrier single-buffer glds —
// the measured-best structure).
// mode 0: qb[l][c] = (xt Wq^T + bq) * QSCALE           (unswizzled)
// mode 1: kb[l][c] =  xt Wk^T + bk   (stored with n ^= (m&7)<<3 swizzle)
// mode 2: vb[c][l] =  Wv xt^T + bv   (stored with n ^= (m&7)<<3 swizzle)
// =====================================================================
__global__ __launch_bounds__(256) void qkv_gemm(
    const unsigned short* __restrict__ xt,
    const unsigned short* __restrict__ wq, const unsigned short* __restrict__ wk,
    const unsigned short* __restrict__ wv,
    const float* __restrict__ bq, const float* __restrict__ bk,
    const float* __restrict__ bv,
    unsigned short* __restrict__ qb, unsigned short* __restrict__ kb,
    unsigned short* __restrict__ vb)
{
    __shared__ unsigned short As[128][32];
    __shared__ unsigned short Bs[128][32];

    const int mode = blockIdx.z >> 2;
    const int b    = blockIdx.z & 3;
    const size_t LC = (size_t)L_ * C_;

    const unsigned short *A, *Bt;
    const float* bias;
    unsigned short* Out;
    float scale = 1.0f;
    int m0, n0, oN, biasN;
    if (mode == 0) {
        A = xt + (size_t)b * LC; Bt = wq; bias = bq; Out = qb + (size_t)b * LC;
        m0 = blockIdx.y * 128; n0 = blockIdx.x * 128; oN = C_; biasN = 1;
        scale = QSCALE;
    } else if (mode == 1) {
        A = xt + (size_t)b * LC; Bt = wk; bias = bk; Out = kb + (size_t)b * LC;
        m0 = blockIdx.y * 128; n0 = blockIdx.x * 128; oN = C_; biasN = 1;
    } else {
        A = wv; Bt = xt + (size_t)b * LC; bias = bv; Out = vb + (size_t)b * LC;
        m0 = blockIdx.x * 128; n0 = blockIdx.y * 128; oN = L_; biasN = 0;
    }
    const int doswz = (mode != 0);

    const int t = threadIdx.x;
    const int lane = t & 63, wid = t >> 6;
    const int wm = (wid >> 1) * 64, wn = (wid & 1) * 64;
    const int q16 = lane & 15, g = lane >> 4;

    const int gr = wid * 32 + (lane >> 2);
    const int gc = (lane & 3) * 8;
    const unsigned short* Ap0 = A  + (size_t)(m0 + gr) * C_ + gc;
    const unsigned short* Ap1 = Ap0 + 16 * C_;
    const unsigned short* Bp0 = Bt + (size_t)(n0 + gr) * C_ + gc;
    const unsigned short* Bp1 = Bp0 + 16 * C_;
    unsigned short* lA0 = &As[wid * 32][0];
    unsigned short* lA1 = &As[wid * 32 + 16][0];
    unsigned short* lB0 = &Bs[wid * 32][0];
    unsigned short* lB1 = &Bs[wid * 32 + 16][0];

    f32x4 zero4 = {0.f, 0.f, 0.f, 0.f};
    f32x4 acc[4][4];
    #pragma unroll
    for (int i = 0; i < 4; ++i)
        #pragma unroll
        for (int j = 0; j < 4; ++j) acc[i][j] = zero4;

    for (int k0 = 0; k0 < C_; k0 += 32) {
        __syncthreads();                       // prev tile reads done
        glds16(Ap0 + k0, lA0); glds16(Ap1 + k0, lA1);
        glds16(Bp0 + k0, lB0); glds16(Bp1 + k0, lB1);
        __syncthreads();                       // vmcnt(0) drained before barrier
        bf16x8 af[4], bfr[4];
        #pragma unroll
        for (int i = 0; i < 4; ++i) af[i]  = frag_ld(&As[wm + 16 * i + q16][8 * g]);
        #pragma unroll
        for (int j = 0; j < 4; ++j) bfr[j] = frag_ld(&Bs[wn + 16 * j + q16][8 * g]);
        #pragma unroll
        for (int i = 0; i < 4; ++i)
            #pragma unroll
            for (int j = 0; j < 4; ++j)
                acc[i][j] = __builtin_amdgcn_mfma_f32_16x16x32_bf16(
                    af[i], bfr[j], acc[i][j], 0, 0, 0);
    }

    #pragma unroll
    for (int j = 0; j < 4; ++j) {
        const int n = n0 + wn + 16 * j + q16;
        const float bn = biasN ? bias[n] : 0.f;
        #pragma unroll
        for (int i = 0; i < 4; ++i) {
            #pragma unroll
            for (int r = 0; r < 4; ++r) {
                const int m = m0 + wm + 16 * i + 4 * g + r;
                const float v = acc[i][j][r] + (biasN ? bn : bias[m]);
                const int nn = doswz ? (n ^ ((m & 7) << 3)) : n;
                Out[(size_t)m * oN + nn] = f2bf_hw(v * scale);
            }
        }
    }
}

// =====================================================================
// gemm_out: out(B,C,L) f32 = Wo @ att^T + bo + x  (reg-prefetch staging —
// the measured-good r4 structure)
// =====================================================================
__global__ __launch_bounds__(256) void gemm_out(
    const unsigned short* __restrict__ A,
    const unsigned short* __restrict__ Bt,
    const float* __restrict__ bias,
    float* __restrict__ Out, const float* __restrict__ resid)
{
    __shared__ unsigned short As[128][40];
    __shared__ unsigned short Bs[128][40];

    const int bz = blockIdx.z;
    const size_t LC = (size_t)L_ * C_;
    Bt    += (size_t)bz * LC;
    Out   += (size_t)bz * LC;
    resid += (size_t)bz * LC;

    const int n0 = blockIdx.x * 128;   // l
    const int m0 = blockIdx.y * 128;   // co
    const int t  = threadIdx.x;
    const int lane = t & 63, wid = t >> 6;
    const int wm = (wid >> 1) * 64, wn = (wid & 1) * 64;
    const int q16 = lane & 15, g = lane >> 4;

    const int srow = t >> 1;
    const int scol = (t & 1) * 16;
    const unsigned short* Ap = A  + (size_t)(m0 + srow) * C_ + scol;
    const unsigned short* Bp = Bt + (size_t)(n0 + srow) * C_ + scol;

    f32x4 zero4 = {0.f, 0.f, 0.f, 0.f};
    f32x4 acc[4][4];
    #pragma unroll
    for (int i = 0; i < 4; ++i)
        #pragma unroll
        for (int j = 0; j < 4; ++j) acc[i][j] = zero4;

    uint4 ar0 = *reinterpret_cast<const uint4*>(Ap);
    uint4 ar1 = *reinterpret_cast<const uint4*>(Ap + 8);
    uint4 br0 = *reinterpret_cast<const uint4*>(Bp);
    uint4 br1 = *reinterpret_cast<const uint4*>(Bp + 8);

    for (int k0 = 0; k0 < C_; k0 += 32) {
        __syncthreads();
        *reinterpret_cast<uint4*>(&As[srow][scol])     = ar0;
        *reinterpret_cast<uint4*>(&As[srow][scol + 8]) = ar1;
        *reinterpret_cast<uint4*>(&Bs[srow][scol])     = br0;
        *reinterpret_cast<uint4*>(&Bs[srow][scol + 8]) = br1;
        __syncthreads();
        if (k0 + 32 < C_) {
            ar0 = *reinterpret_cast<const uint4*>(Ap + k0 + 32);
            ar1 = *reinterpret_cast<const uint4*>(Ap + k0 + 40);
            br0 = *reinterpret_cast<const uint4*>(Bp + k0 + 32);
            br1 = *reinterpret_cast<const uint4*>(Bp + k0 + 40);
        }
        bf16x8 af[4], bfr[4];
        #pragma unroll
        for (int i = 0; i < 4; ++i) af[i]  = frag_ld(&As[wm + 16 * i + q16][8 * g]);
        #pragma unroll
        for (int j = 0; j < 4; ++j) bfr[j] = frag_ld(&Bs[wn + 16 * j + q16][8 * g]);
        #pragma unroll
        for (int i = 0; i < 4; ++i)
            #pragma unroll
            for (int j = 0; j < 4; ++j)
                acc[i][j] = __builtin_amdgcn_mfma_f32_16x16x32_bf16(
                    af[i], bfr[j], acc[i][j], 0, 0, 0);
    }

    #pragma unroll
    for (int j = 0; j < 4; ++j) {
        const int n = n0 + wn + 16 * j + q16;
        #pragma unroll
        for (int i = 0; i < 4; ++i) {
            #pragma unroll
            for (int r = 0; r < 4; ++r) {
                const int m = m0 + wm + 16 * i + 4 * g + r;
                const size_t off = (size_t)m * L_ + n;
                Out[off] = acc[i][j][r] + bias[m] + resid[off];
            }
        }
    }
}

// =====================================================================
// attn_mfma: 32x32x16 MFMA flash attention — exact r7 structure (the
// measured-best at 75.3 us; r10's setprio + packed-sub variants regressed
// to 81 and are reverted). In-register P via cvt_pk + permlane32_swap;
// K/V glds double-buffered [64][64] (global pre-swizzled col^=(row&7)<<3).
// Block = (b, h, 128 q); 4 waves x 32 q; grid 512.
// =====================================================================
__global__ __launch_bounds__(256) void attn_mfma(
    const unsigned short* __restrict__ Qb,
    const unsigned short* __restrict__ Kb,
    const unsigned short* __restrict__ Vb,
    unsigned short* __restrict__ Ab)
{
    __shared__ unsigned short Ks[2][64][64];   // [buf][k][d]  swizzled cols
    __shared__ unsigned short Vs[2][64][64];   // [buf][d][k]  swizzled cols

    const int q0 = blockIdx.x * 128;
    const int h  = blockIdx.y;
    const int b  = blockIdx.z;
    const int t  = threadIdx.x, lane = t & 63, wid = t >> 6;
    const int q32 = lane & 31, hi = lane >> 5;
    const int swz = (q32 & 7) << 3;

    const unsigned short* Qg = Qb + (size_t)b * L_ * C_;
    const unsigned short* Kg = Kb + (size_t)b * L_ * C_ + h * D_;
    const unsigned short* Vg = Vb + ((size_t)b * C_ + h * D_) * L_;
    unsigned short* Ag       = Ab + (size_t)b * L_ * C_;

    // Q B-frags (col = q32, k-dim = d), held all block
    bf16x8 qf[4];
    {
        const unsigned short* qp =
            Qg + (size_t)(q0 + 32 * wid + q32) * C_ + h * D_ + 8 * hi;
        #pragma unroll
        for (int c = 0; c < 4; ++c) qf[c] = frag_ld(qp + 16 * c);
    }

    // ones B-frag: column 0 = 1.0 (lanes with q32==0)
    const unsigned ow = (q32 == 0) ? 0x3F803F80u : 0u;
    const uint4 ov = make_uint4(ow, ow, ow, ow);
    const bf16x8 onesf = __builtin_bit_cast(bf16x8, ov);

    f32x16 zero16 = {0.f,0.f,0.f,0.f,0.f,0.f,0.f,0.f,
                     0.f,0.f,0.f,0.f,0.f,0.f,0.f,0.f};
    f32x16 oacc0 = zero16, oacc1 = zero16, lacc = zero16;
    float m_s = -INFINITY;

    const int gr8 = lane >> 3;
    const int gc8 = (lane & 7) * 8;
    const unsigned short* Kp0 = Kg + (size_t)(16 * wid + gr8) * C_ + gc8;
    const unsigned short* Kp1 = Kp0 + (size_t)8 * C_;
    const unsigned short* Vp0 = Vg + (size_t)(16 * wid + gr8) * L_ + gc8;
    const unsigned short* Vp1 = Vp0 + (size_t)8 * L_;

    glds16(Kp0, &Ks[0][16 * wid][0]);
    glds16(Kp1, &Ks[0][16 * wid + 8][0]);
    glds16(Vp0, &Vs[0][16 * wid][0]);
    glds16(Vp1, &Vs[0][16 * wid + 8][0]);
    __syncthreads();

    #pragma unroll 2
    for (int kt = 0; kt < 32; ++kt) {
        const int cur = kt & 1;
        if (kt < 31) {   // issue next tile's staging early (hides under compute)
            const size_t ko = (size_t)(kt + 1) * 64;
            glds16(Kp0 + ko * C_, &Ks[cur ^ 1][16 * wid][0]);
            glds16(Kp1 + ko * C_, &Ks[cur ^ 1][16 * wid + 8][0]);
            glds16(Vp0 + ko,      &Vs[cur ^ 1][16 * wid][0]);
            glds16(Vp1 + ko,      &Vs[cur ^ 1][16 * wid + 8][0]);
        }

        // ---- S^T = K Q^T : s0/s1 = k-halves; lane owns q = q32 ----
        f32x16 s0 = zero16, s1 = zero16;
        #pragma unroll
        for (int c = 0; c < 4; ++c) {
            const int co = (16 * c + 8 * hi) ^ swz;
            bf16x8 k0 = frag_ld(&Ks[cur][q32][co]);
            bf16x8 k1 = frag_ld(&Ks[cur][32 + q32][co]);
            s0 = __builtin_amdgcn_mfma_f32_32x32x16_bf16(k0, qf[c], s0, 0, 0, 0);
            s1 = __builtin_amdgcn_mfma_f32_32x32x16_bf16(k1, qf[c], s1, 0, 0, 0);
        }

        // ---- in-lane max over 32 values + 1 cross shfl ----
        const float a0 = fmax3(s0[0], s0[1], s0[2]);
        const float a1 = fmax3(s0[3], s0[4], s0[5]);
        const float a2 = fmax3(s0[6], s0[7], s0[8]);
        const float a3 = fmax3(s0[9], s0[10], s0[11]);
        const float a4 = fmax3(s0[12], s0[13], s0[14]);
        const float a5 = fmax3(s0[15], s1[0], s1[1]);
        const float a6 = fmax3(s1[2], s1[3], s1[4]);
        const float a7 = fmax3(s1[5], s1[6], s1[7]);
        const float a8 = fmax3(s1[8], s1[9], s1[10]);
        const float a9 = fmax3(s1[11], s1[12], s1[13]);
        const float b0 = fmax3(a0, a1, a2);
        const float b1 = fmax3(a3, a4, a5);
        const float b2 = fmax3(a6, a7, a8);
        const float b3 = fmax3(a9, s1[14], s1[15]);
        float pm = fmaxf(fmaxf(b0, b1), fmaxf(b2, b3));
        pm = fmaxf(pm, __shfl_xor(pm, 32));

        // ---- defer-max rescale (rare) ----
        if (!__all(pm - m_s <= DEFER_THR)) {
            const float mn   = fmaxf(m_s, pm);
            const float corr = exp2f(m_s - mn);
            m_s = mn;
            #pragma unroll
            for (int r = 0; r < 16; ++r) {
                const float cr = __shfl(corr, (r & 3) + 8 * (r >> 2) + 4 * hi);
                oacc0[r] *= cr; oacc1[r] *= cr; lacc[r] *= cr;
            }
        }

        // ---- exp2 (all 32 values are row q32: m_s is lane-local) ----
        float p0[16], p1[16];
        #pragma unroll
        for (int r = 0; r < 16; ++r) {
            p0[r] = exp2f(s0[r] - m_s);
            p1[r] = exp2f(s1[r] - m_s);
        }

        // ---- pack P -> A-frags (cvt_pk + permlane32_swap), PV, l-sum ----
        #pragma unroll
        for (int ks = 0; ks < 4; ++ks) {
            const int rb = 8 * (ks & 1);
            #define PPX(i) ((ks < 2) ? p0[(i)] : p1[(i)])
            unsigned wa = cvt_pk(PPX(rb + 0), PPX(rb + 1));
            unsigned wb = cvt_pk(PPX(rb + 2), PPX(rb + 3));
            unsigned wc = cvt_pk(PPX(rb + 4), PPX(rb + 5));
            unsigned wd = cvt_pk(PPX(rb + 6), PPX(rb + 7));
            #undef PPX
            asm volatile("v_permlane32_swap_b32 %0, %1" : "+v"(wa), "+v"(wc));
            asm volatile("v_permlane32_swap_b32 %0, %1" : "+v"(wb), "+v"(wd));
            const uint4 pv = make_uint4(wa, wb, wc, wd);
            const bf16x8 paf = __builtin_bit_cast(bf16x8, pv);

            const int co = (16 * ks + 8 * hi) ^ swz;
            bf16x8 v0 = frag_ld(&Vs[cur][q32][co]);
            bf16x8 v1 = frag_ld(&Vs[cur][32 + q32][co]);
            oacc0 = __builtin_amdgcn_mfma_f32_32x32x16_bf16(paf, v0, oacc0, 0, 0, 0);
            oacc1 = __builtin_amdgcn_mfma_f32_32x32x16_bf16(paf, v1, oacc1, 0, 0, 0);
            lacc  = __builtin_amdgcn_mfma_f32_32x32x16_bf16(paf, onesf, lacc, 0, 0, 0);
        }

        __syncthreads();   // next tile staged (vmcnt drained) + reads done
    }

    // ---- epilogue: l from lacc col 0 (lanes 0/32), normalize, store ----
    #pragma unroll
    for (int r = 0; r < 16; ++r) {
        const float lv  = __shfl(lacc[r], hi << 5);
        const float inv = 1.f / lv;
        const int q = q0 + 32 * wid + (r & 3) + 8 * (r >> 2) + 4 * hi;
        unsigned short* op = Ag + (size_t)q * C_ + h * D_ + q32;
        op[0]  = f2bf_hw(oacc0[r] * inv);
        op[32] = f2bf_hw(oacc1[r] * inv);
    }
}

// =====================================================================
extern "C" void kernel_launch(void* const* d_in, const int* in_sizes, int n_in,
                              void* d_out, int out_size, void* d_ws, size_t ws_size,
                              hipStream_t stream)
{
    const float* x  = (const float*)d_in[0];
    const float* Wq = (const float*)d_in[1];
    const float* bq = (const float*)d_in[2];
    const float* Wk = (const float*)d_in[3];
    const float* bk = (const float*)d_in[4];
    const float* Wv = (const float*)d_in[5];
    const float* bv = (const float*)d_in[6];
    const float* Wo = (const float*)d_in[7];
    const float* bo = (const float*)d_in[8];
    float* out = (float*)d_out;

    const size_t NB = (size_t)B_ * L_ * C_;
    const size_t NW = (size_t)C_ * C_;
    unsigned short* ws16 = (unsigned short*)d_ws;
    unsigned short* xt  = ws16;
    unsigned short* qb  = xt  + NB;
    unsigned short* kb  = qb  + NB;
    unsigned short* vb  = kb  + NB;
    unsigned short* att = vb  + NB;
    unsigned short* wqb = att + NB;
    unsigned short* wkb = wqb + NW;
    unsigned short* wvb = wkb + NW;
    unsigned short* wob = wvb + NW;

    prep<<<dim3(32, 8, 2 * B_), 256, 0, stream>>>(
        x, Wq, Wk, Wv, Wo, xt, wqb, wkb, wvb, wob);

    qkv_gemm<<<dim3(4, 16, 3 * B_), 256, 0, stream>>>(
        xt, wqb, wkb, wvb, bq, bk, bv, qb, kb, vb);

    attn_mfma<<<dim3(L_ / 128, H_, B_), 256, 0, stream>>>(qb, kb, vb, att);

    gemm_out<<<dim3(16, 4, B_), 256, 0, stream>>>(wob, att, bo, out, x);
}